// Round 1
// baseline (2975.389 us; speedup 1.0000x reference)
//
#include <hip/hip_runtime.h>
#include <cmath>

// Problem constants: b=4, c=512, h=w=64 -> n=4096, groups=32 (16 ch/group)
#define NB 4
#define NC 512
#define NN 4096
#define OC3 1536
#define ATTN_SCALE 0.04419417382415922f  // 512^-0.5

// ---------------------------------------------------------------------------
// Kernel 1: GroupNorm stats -> per-channel scale/shift
// ss[b*512+c]        = rstd * gamma[c]
// ss[2048 + b*512+c] = beta[c] - mean * rstd * gamma[c]
// ---------------------------------------------------------------------------
__global__ __launch_bounds__(256) void gn_stats_kernel(
    const float* __restrict__ x, const float* __restrict__ gw,
    const float* __restrict__ gb, float* __restrict__ ss)
{
    int bg = blockIdx.x;            // b*32 + g
    int b = bg >> 5, g = bg & 31;
    const float* xp = x + ((size_t)(b * NC + g * 16)) * NN;  // 16 contiguous channels
    float s1 = 0.f, s2 = 0.f;
    for (int i = threadIdx.x; i < 16 * NN; i += 256) {
        float v = xp[i];
        s1 += v; s2 += v * v;
    }
#pragma unroll
    for (int off = 32; off; off >>= 1) {
        s1 += __shfl_xor(s1, off, 64);
        s2 += __shfl_xor(s2, off, 64);
    }
    __shared__ float r1[4], r2[4];
    int lane = threadIdx.x & 63, w = threadIdx.x >> 6;
    if (lane == 0) { r1[w] = s1; r2[w] = s2; }
    __syncthreads();
    if (threadIdx.x < 16) {
        float t1 = r1[0] + r1[1] + r1[2] + r1[3];
        float t2 = r2[0] + r2[1] + r2[2] + r2[3];
        float mean = t1 * (1.0f / 65536.0f);
        float var  = t2 * (1.0f / 65536.0f) - mean * mean;
        float rstd = rsqrtf(var + 1e-5f);
        int c = g * 16 + threadIdx.x;
        float sc = rstd * gw[c];
        ss[b * NC + c] = sc;
        ss[2048 + b * NC + c] = gb[c] - mean * sc;
    }
}

// ---------------------------------------------------------------------------
// Kernel 2: QKV GEMM with fused GroupNorm on B-load.
// C[o,p] = sum_k W[o,k] * (x[b,k,p]*scale[k] + shift[k]) + bias[o]
// Epilogue routes: o<512 -> qt[b,p,o] ; 512..1023 -> kbuf[b,o-512,p] ;
//                  >=1024 -> vt[b,p,o-1024]
// ---------------------------------------------------------------------------
__global__ __launch_bounds__(256) void qkv_gemm_kernel(
    const float* __restrict__ W, const float* __restrict__ x,
    const float* __restrict__ ss, const float* __restrict__ bias,
    float* __restrict__ qt, float* __restrict__ kbuf, float* __restrict__ vt)
{
    int bb = blockIdx.z;
    int otile = blockIdx.y * 64;
    int ptile = blockIdx.x * 64;
    int t = threadIdx.x;
    int tx = t & 15, ty = t >> 4;

    __shared__ float As[64][17];
    __shared__ float Bs[16][64];
    float acc[4][4] = {};
    const float* xb = x + (size_t)bb * NC * NN;
    const float* scp = ss + bb * NC;
    const float* shp = ss + 2048 + bb * NC;

    for (int k0 = 0; k0 < NC; k0 += 16) {
#pragma unroll
        for (int i = 0; i < 4; ++i) {
            int idx = t + i * 256;
            int r = idx >> 4, kk = idx & 15;
            As[r][kk] = W[(size_t)(otile + r) * NC + k0 + kk];
        }
#pragma unroll
        for (int i = 0; i < 4; ++i) {
            int idx = t + i * 256;
            int r = idx >> 6, cc = idx & 63;
            int k = k0 + r;
            Bs[r][cc] = xb[(size_t)k * NN + ptile + cc] * scp[k] + shp[k];
        }
        __syncthreads();
#pragma unroll
        for (int kk = 0; kk < 16; ++kk) {
            float a[4], bvr[4];
#pragma unroll
            for (int i = 0; i < 4; ++i) a[i] = As[ty * 4 + i][kk];
#pragma unroll
            for (int j = 0; j < 4; ++j) bvr[j] = Bs[kk][tx * 4 + j];
#pragma unroll
            for (int i = 0; i < 4; ++i)
#pragma unroll
                for (int j = 0; j < 4; ++j) acc[i][j] += a[i] * bvr[j];
        }
        __syncthreads();
    }

#pragma unroll
    for (int i = 0; i < 4; ++i) {
        int o = otile + ty * 4 + i;
        float bv = bias[o];
#pragma unroll
        for (int j = 0; j < 4; ++j) {
            int p = ptile + tx * 4 + j;
            float v = acc[i][j] + bv;
            if (o < 512)
                qt[((size_t)(bb * NN + p)) * NC + o] = v;
            else if (o < 1024)
                kbuf[((size_t)(bb * NC + (o - 512))) * NN + p] = v;
            else
                vt[((size_t)(bb * NN + p)) * NC + (o - 1024)] = v;
        }
    }
}

// ---------------------------------------------------------------------------
// Kernel 3: S[p,m] = ATTN_SCALE * sum_c qt[p,c] * kbuf[c,m]   (one batch)
// ---------------------------------------------------------------------------
__global__ __launch_bounds__(256) void qk_gemm_kernel(
    const float* __restrict__ A, const float* __restrict__ Bm, float* __restrict__ S)
{
    int mtile = blockIdx.x * 64;   // m
    int ptile = blockIdx.y * 64;   // p
    int t = threadIdx.x;
    int tx = t & 15, ty = t >> 4;

    __shared__ float As[64][17];
    __shared__ float Bs[16][64];
    float acc[4][4] = {};

    for (int k0 = 0; k0 < NC; k0 += 16) {
#pragma unroll
        for (int i = 0; i < 4; ++i) {
            int idx = t + i * 256;
            int r = idx >> 4, kk = idx & 15;
            As[r][kk] = A[(size_t)(ptile + r) * NC + k0 + kk];
        }
#pragma unroll
        for (int i = 0; i < 4; ++i) {
            int idx = t + i * 256;
            int r = idx >> 6, cc = idx & 63;
            Bs[r][cc] = Bm[(size_t)(k0 + r) * NN + mtile + cc];
        }
        __syncthreads();
#pragma unroll
        for (int kk = 0; kk < 16; ++kk) {
            float a[4], bvr[4];
#pragma unroll
            for (int i = 0; i < 4; ++i) a[i] = As[ty * 4 + i][kk];
#pragma unroll
            for (int j = 0; j < 4; ++j) bvr[j] = Bs[kk][tx * 4 + j];
#pragma unroll
            for (int i = 0; i < 4; ++i)
#pragma unroll
                for (int j = 0; j < 4; ++j) acc[i][j] += a[i] * bvr[j];
        }
        __syncthreads();
    }
#pragma unroll
    for (int i = 0; i < 4; ++i) {
        int p = ptile + ty * 4 + i;
#pragma unroll
        for (int j = 0; j < 4; ++j) {
            int m = mtile + tx * 4 + j;
            S[(size_t)p * NN + m] = acc[i][j] * ATTN_SCALE;
        }
    }
}

// ---------------------------------------------------------------------------
// Kernel 4: row softmax over S (4096 cols), row fully in registers (16/thread)
// ---------------------------------------------------------------------------
__global__ __launch_bounds__(256) void softmax_kernel(float* __restrict__ S)
{
    int row = blockIdx.x;
    float* Sr = S + (size_t)row * NN;
    int t = threadIdx.x;
    float v[16];
    float m = -INFINITY;
#pragma unroll
    for (int i = 0; i < 16; ++i) {
        v[i] = Sr[t + i * 256];
        m = fmaxf(m, v[i]);
    }
#pragma unroll
    for (int off = 32; off; off >>= 1) m = fmaxf(m, __shfl_xor(m, off, 64));
    __shared__ float red[4];
    int lane = t & 63, w = t >> 6;
    if (lane == 0) red[w] = m;
    __syncthreads();
    m = fmaxf(fmaxf(red[0], red[1]), fmaxf(red[2], red[3]));
    __syncthreads();

    float s = 0.f;
#pragma unroll
    for (int i = 0; i < 16; ++i) {
        v[i] = __expf(v[i] - m);
        s += v[i];
    }
#pragma unroll
    for (int off = 32; off; off >>= 1) s += __shfl_xor(s, off, 64);
    if (lane == 0) red[w] = s;
    __syncthreads();
    s = red[0] + red[1] + red[2] + red[3];
    float inv = 1.0f / s;
#pragma unroll
    for (int i = 0; i < 16; ++i) Sr[t + i * 256] = v[i] * inv;
}

// ---------------------------------------------------------------------------
// Kernel 5: O[p,c] = sum_m P[p,m] * vt[m,c]   (one batch; K=4096)
// ---------------------------------------------------------------------------
__global__ __launch_bounds__(256) void pv_gemm_kernel(
    const float* __restrict__ P, const float* __restrict__ V, float* __restrict__ O)
{
    int ctile = blockIdx.x * 64;   // c (N=512)
    int ptile = blockIdx.y * 64;   // p (M=4096)
    int t = threadIdx.x;
    int tx = t & 15, ty = t >> 4;

    __shared__ float As[64][17];
    __shared__ float Bs[16][64];
    float acc[4][4] = {};

    for (int k0 = 0; k0 < NN; k0 += 16) {
#pragma unroll
        for (int i = 0; i < 4; ++i) {
            int idx = t + i * 256;
            int r = idx >> 4, kk = idx & 15;
            As[r][kk] = P[(size_t)(ptile + r) * NN + k0 + kk];
        }
#pragma unroll
        for (int i = 0; i < 4; ++i) {
            int idx = t + i * 256;
            int r = idx >> 6, cc = idx & 63;
            Bs[r][cc] = V[(size_t)(k0 + r) * NC + ctile + cc];
        }
        __syncthreads();
#pragma unroll
        for (int kk = 0; kk < 16; ++kk) {
            float a[4], bvr[4];
#pragma unroll
            for (int i = 0; i < 4; ++i) a[i] = As[ty * 4 + i][kk];
#pragma unroll
            for (int j = 0; j < 4; ++j) bvr[j] = Bs[kk][tx * 4 + j];
#pragma unroll
            for (int i = 0; i < 4; ++i)
#pragma unroll
                for (int j = 0; j < 4; ++j) acc[i][j] += a[i] * bvr[j];
        }
        __syncthreads();
    }
#pragma unroll
    for (int i = 0; i < 4; ++i) {
        int p = ptile + ty * 4 + i;
#pragma unroll
        for (int j = 0; j < 4; ++j) {
            int c = ctile + tx * 4 + j;
            O[(size_t)p * NC + c] = acc[i][j];
        }
    }
}

// ---------------------------------------------------------------------------
// Kernel 6: out[b,o,p] = sum_c W2[o,c]*O[b,p,c] + out_b[o] + x[b,o,p]  (NT GEMM)
// ---------------------------------------------------------------------------
__global__ __launch_bounds__(256) void out_gemm_kernel(
    const float* __restrict__ W2, const float* __restrict__ O,
    const float* __restrict__ ob, const float* __restrict__ x, float* __restrict__ out)
{
    int bb = blockIdx.z;
    int ptile = blockIdx.x * 64;   // p (N=4096)
    int otile = blockIdx.y * 64;   // o (M=512)
    int t = threadIdx.x;
    int tx = t & 15, ty = t >> 4;

    __shared__ float As[64][17];
    __shared__ float Bs[16][65];
    float acc[4][4] = {};
    const float* Ob = O + (size_t)bb * NN * NC;

    for (int k0 = 0; k0 < NC; k0 += 16) {
#pragma unroll
        for (int i = 0; i < 4; ++i) {
            int idx = t + i * 256;
            int r = idx >> 4, kk = idx & 15;
            As[r][kk] = W2[(size_t)(otile + r) * NC + k0 + kk];
        }
#pragma unroll
        for (int i = 0; i < 4; ++i) {
            int idx = t + i * 256;
            int jj = idx >> 4, kk = idx & 15;   // B^T storage: O[p, c]
            Bs[kk][jj] = Ob[(size_t)(ptile + jj) * NC + k0 + kk];
        }
        __syncthreads();
#pragma unroll
        for (int kk = 0; kk < 16; ++kk) {
            float a[4], bvr[4];
#pragma unroll
            for (int i = 0; i < 4; ++i) a[i] = As[ty * 4 + i][kk];
#pragma unroll
            for (int j = 0; j < 4; ++j) bvr[j] = Bs[kk][tx * 4 + j];
#pragma unroll
            for (int i = 0; i < 4; ++i)
#pragma unroll
                for (int j = 0; j < 4; ++j) acc[i][j] += a[i] * bvr[j];
        }
        __syncthreads();
    }
#pragma unroll
    for (int i = 0; i < 4; ++i) {
        int o = otile + ty * 4 + i;
        float bv = ob[o];
#pragma unroll
        for (int j = 0; j < 4; ++j) {
            int p = ptile + tx * 4 + j;
            size_t idx = ((size_t)bb * NC + o) * NN + p;
            out[idx] = acc[i][j] + bv + x[idx];
        }
    }
}

// ---------------------------------------------------------------------------
extern "C" void kernel_launch(void* const* d_in, const int* in_sizes, int n_in,
                              void* d_out, int out_size, void* d_ws, size_t ws_size,
                              hipStream_t stream)
{
    const float* x     = (const float*)d_in[0];
    const float* gn_w  = (const float*)d_in[1];
    const float* gn_b  = (const float*)d_in[2];
    const float* qkv_w = (const float*)d_in[3];
    const float* qkv_b = (const float*)d_in[4];
    const float* out_w = (const float*)d_in[5];
    const float* out_b = (const float*)d_in[6];
    float* out = (float*)d_out;

    float* ws = (float*)d_ws;
    const size_t bnc = (size_t)NB * NN * NC;  // 8,388,608
    float* ss   = ws;              // 4096 floats (scale@0, shift@2048)
    float* qt   = ws + 4096;       // (b, n, c)
    float* kbuf = qt + bnc;        // (b, c, n)
    float* vt   = kbuf + bnc;      // (b, n, c)
    float* obuf = vt + bnc;        // (b, n, c)
    float* S    = obuf + bnc;      // 4096 x 4096, one batch at a time

    gn_stats_kernel<<<NB * 32, 256, 0, stream>>>(x, gn_w, gn_b, ss);
    qkv_gemm_kernel<<<dim3(NN / 64, OC3 / 64, NB), 256, 0, stream>>>(
        qkv_w, x, ss, qkv_b, qt, kbuf, vt);
    for (int b = 0; b < NB; ++b) {
        const float* qb = qt + (size_t)b * NN * NC;
        const float* kb = kbuf + (size_t)b * NC * NN;
        const float* vb = vt + (size_t)b * NN * NC;
        float* ob2 = obuf + (size_t)b * NN * NC;
        qk_gemm_kernel<<<dim3(NN / 64, NN / 64), 256, 0, stream>>>(qb, kb, S);
        softmax_kernel<<<NN, 256, 0, stream>>>(S);
        pv_gemm_kernel<<<dim3(NC / 64, NN / 64), 256, 0, stream>>>(S, vb, ob2);
    }
    out_gemm_kernel<<<dim3(NN / 64, NC / 64, NB), 256, 0, stream>>>(
        out_w, obuf, out_b, x, out);
}

// Round 2
// 754.665 us; speedup vs baseline: 3.9427x; 3.9427x over previous
//
#include <hip/hip_runtime.h>
#include <cmath>

// b=4, c=512, n=4096, groups=32 (16 ch/group)
#define NB 4
#define NC 512
#define NN 4096
#define ATTN_SCALE 0.04419417382415922f  // 512^-0.5

typedef __bf16 bf16x8 __attribute__((ext_vector_type(8)));
typedef float floatx4 __attribute__((ext_vector_type(4)));

__device__ __forceinline__ unsigned short f2bf(float f) {
    union { float f; unsigned int u; } v; v.f = f;
    return (unsigned short)((v.u + 0x7fffu + ((v.u >> 16) & 1u)) >> 16);
}

__device__ __forceinline__ void gload_lds16(const unsigned short* gp, unsigned short* lp) {
    __builtin_amdgcn_global_load_lds(
        (const __attribute__((address_space(1))) void*)gp,
        (__attribute__((address_space(3))) void*)lp, 16, 0, 0);
}

// ---------------------------------------------------------------------------
// Kernel 1: GroupNorm stats -> per-channel scale/shift (fp32)
// ---------------------------------------------------------------------------
__global__ __launch_bounds__(256) void gn_stats_kernel(
    const float* __restrict__ x, const float* __restrict__ gw,
    const float* __restrict__ gb, float* __restrict__ ss)
{
    int bg = blockIdx.x;            // b*32 + g
    int b = bg >> 5, g = bg & 31;
    const float* xp = x + ((size_t)(b * NC + g * 16)) * NN;
    float s1 = 0.f, s2 = 0.f;
    for (int i = threadIdx.x; i < 16 * NN; i += 256) {
        float v = xp[i];
        s1 += v; s2 += v * v;
    }
#pragma unroll
    for (int off = 32; off; off >>= 1) {
        s1 += __shfl_xor(s1, off, 64);
        s2 += __shfl_xor(s2, off, 64);
    }
    __shared__ float r1[4], r2[4];
    int lane = threadIdx.x & 63, w = threadIdx.x >> 6;
    if (lane == 0) { r1[w] = s1; r2[w] = s2; }
    __syncthreads();
    if (threadIdx.x < 16) {
        float t1 = r1[0] + r1[1] + r1[2] + r1[3];
        float t2 = r2[0] + r2[1] + r2[2] + r2[3];
        float mean = t1 * (1.0f / 65536.0f);
        float var  = t2 * (1.0f / 65536.0f) - mean * mean;
        float rstd = rsqrtf(var + 1e-5f);
        int c = g * 16 + threadIdx.x;
        float sc = rstd * gw[c];
        ss[b * NC + c] = sc;
        ss[2048 + b * NC + c] = gb[c] - mean * sc;
    }
}

// ---------------------------------------------------------------------------
// Kernel 2: convert weights fp32 -> bf16 (qkv_w 1536x512, out_w 512x512)
// ---------------------------------------------------------------------------
__global__ __launch_bounds__(256) void wconv_kernel(
    const float* __restrict__ qkv_w, const float* __restrict__ out_w,
    unsigned short* __restrict__ wq, unsigned short* __restrict__ wo)
{
    int i = blockIdx.x * 256 + threadIdx.x;
    const int NQ = 1536 * 512;
    if (i < NQ) wq[i] = f2bf(qkv_w[i]);
    else        wo[i - NQ] = f2bf(out_w[i - NQ]);
}

// ---------------------------------------------------------------------------
// Kernel 3: normalize + transpose: x (b,c,n) fp32 -> h_t (b,n,c) bf16
// ---------------------------------------------------------------------------
__global__ __launch_bounds__(256) void htnorm_kernel(
    const float* __restrict__ x, const float* __restrict__ ss,
    unsigned short* __restrict__ ht)
{
    int b = blockIdx.z;
    int c0 = blockIdx.y * 32, n0 = blockIdx.x * 32;
    __shared__ float T[32][33];
    int tx = threadIdx.x & 31, ty = threadIdx.x >> 5;   // ty 0..7
    const float* xb = x + ((size_t)b * NC + c0) * NN;
    const float* sc = ss + b * NC + c0;
    const float* sh = ss + 2048 + b * NC + c0;
#pragma unroll
    for (int i = 0; i < 4; ++i) {
        int c = ty + i * 8;
        T[c][tx] = xb[(size_t)c * NN + n0 + tx] * sc[c] + sh[c];
    }
    __syncthreads();
    unsigned short* hb = ht + ((size_t)b * NN + n0) * NC + c0;
#pragma unroll
    for (int i = 0; i < 4; ++i) {
        int n = ty + i * 8;
        hb[(size_t)n * NC + tx] = f2bf(T[tx][n]);
    }
}

// ---------------------------------------------------------------------------
// MFMA NT GEMM: C[m,n] = sum_k A[m,k]*B[n,k], 128x128 block tile, BK=32.
// MODE 0: qkv q/k   M=4096 N=1024 K=512  A=ht(+z) B=wqk       -> qt/kt bf16 +bias
// MODE 1: qkv v     M=512  N=4096 K=512  A=wv     B=ht(+z)    -> vt (c,p) bf16 +bias
// MODE 2: QK^T      M=4096 N=4096 K=512  A=qt     B=kt        -> S fp32 *scale
// MODE 3: PV        M=4096 N=512  K=4096 A=P      B=vt        -> O (p,c) bf16
// MODE 4: out proj  M=512  N=4096 K=512  A=wo     B=O(+z)     -> out fp32 +bias+res
// ---------------------------------------------------------------------------
template<int MODE>
__global__ __launch_bounds__(256) void mfma_gemm(
    const unsigned short* __restrict__ Abase,
    const unsigned short* __restrict__ Bbase,
    const float* __restrict__ e0, const float* __restrict__ e1,
    float* __restrict__ outf,
    unsigned short* __restrict__ ob0, unsigned short* __restrict__ ob1)
{
    constexpr int K = (MODE == 3) ? 4096 : 512;
    const int z = blockIdx.z;
    const size_t bnc = (size_t)NN * NC;   // 4096*512 per batch

    const unsigned short* A;
    const unsigned short* B;
    if constexpr (MODE == 0)      { A = Abase + (size_t)z * bnc; B = Bbase; }
    else if constexpr (MODE == 1) { A = Abase; B = Bbase + (size_t)z * bnc; }
    else if constexpr (MODE == 4) { A = Abase; B = Bbase + (size_t)z * bnc; }
    else                          { A = Abase; B = Bbase; }   // MODE 2/3 pre-offset

    const int m0 = blockIdx.y * 128;
    const int n0 = blockIdx.x * 128;

    __shared__ __attribute__((aligned(16))) unsigned short As[128 * 32];
    __shared__ __attribute__((aligned(16))) unsigned short Bs[128 * 32];

    const int t = threadIdx.x;
    const int lane = t & 63;
    const int w = t >> 6;
    const int wr = w >> 1, wc = w & 1;

    // staging: wave w covers rows w*16 + lane/4 (and +64), 16B per lane
    const int sr = w * 16 + (lane >> 2);
    const int sc = (lane & 3) * 8;             // element offset within 32
    const int lds_elem = w * 512;              // w*1024 bytes

    floatx4 acc[4][4] = {};

    for (int k0 = 0; k0 < K; k0 += 32) {
        gload_lds16(A + (size_t)(m0 + sr) * K + k0 + sc,       As + lds_elem);
        gload_lds16(A + (size_t)(m0 + 64 + sr) * K + k0 + sc,  As + 2048 + lds_elem);
        gload_lds16(B + (size_t)(n0 + sr) * K + k0 + sc,       Bs + lds_elem);
        gload_lds16(B + (size_t)(n0 + 64 + sr) * K + k0 + sc,  Bs + 2048 + lds_elem);
        __syncthreads();

        bf16x8 af[4], bfr[4];
        const unsigned short* Ab = As + ((wr * 64 + (lane & 15)) * 32) + (lane >> 4) * 8;
        const unsigned short* Bb = Bs + ((wc * 64 + (lane & 15)) * 32) + (lane >> 4) * 8;
#pragma unroll
        for (int i = 0; i < 4; ++i) af[i]  = *(const bf16x8*)(Ab + i * 16 * 32);
#pragma unroll
        for (int j = 0; j < 4; ++j) bfr[j] = *(const bf16x8*)(Bb + j * 16 * 32);
#pragma unroll
        for (int i = 0; i < 4; ++i)
#pragma unroll
            for (int j = 0; j < 4; ++j)
                acc[i][j] = __builtin_amdgcn_mfma_f32_16x16x32_bf16(
                    af[i], bfr[j], acc[i][j], 0, 0, 0);
        __syncthreads();
    }

    // Epilogue. C/D: col = lane&15, row = (lane>>4)*4 + reg
    const int fr = lane >> 4;
    const int fc = lane & 15;
#pragma unroll
    for (int i = 0; i < 4; ++i) {
#pragma unroll
        for (int j = 0; j < 4; ++j) {
            int n = n0 + wc * 64 + j * 16 + fc;
            int mbase = m0 + wr * 64 + i * 16 + fr * 4;
#pragma unroll
            for (int r = 0; r < 4; ++r) {
                int m = mbase + r;
                float val = acc[i][j][r];
                if constexpr (MODE == 0) {
                    val += e0[n];   // qkv bias, o = n in [0,1024)
                    if (n < 512) ob0[((size_t)z * NN + m) * NC + n] = f2bf(val);
                    else         ob1[((size_t)z * NN + m) * NC + (n - 512)] = f2bf(val);
                } else if constexpr (MODE == 1) {
                    val += e0[1024 + m];   // v bias, channel = m
                    ob0[((size_t)z * NC + m) * NN + n] = f2bf(val);
                } else if constexpr (MODE == 2) {
                    outf[(size_t)m * NN + n] = val * ATTN_SCALE;
                } else if constexpr (MODE == 3) {
                    ob0[(size_t)m * NC + n] = f2bf(val);
                } else {   // MODE 4
                    size_t idx = ((size_t)z * NC + m) * NN + n;
                    outf[idx] = val + e0[m] + e1[idx];
                }
            }
        }
    }
}

// ---------------------------------------------------------------------------
// Softmax: row of S (fp32) -> row of P (bf16), row in registers
// ---------------------------------------------------------------------------
__global__ __launch_bounds__(256) void softmax_kernel(
    const float* __restrict__ S, unsigned short* __restrict__ P)
{
    int row = blockIdx.x;
    const float* Sr = S + (size_t)row * NN;
    unsigned short* Pr = P + (size_t)row * NN;
    int t = threadIdx.x;
    float v[16];
    float m = -INFINITY;
#pragma unroll
    for (int i = 0; i < 16; ++i) {
        v[i] = Sr[t + i * 256];
        m = fmaxf(m, v[i]);
    }
#pragma unroll
    for (int off = 32; off; off >>= 1) m = fmaxf(m, __shfl_xor(m, off, 64));
    __shared__ float red[4];
    int lane = t & 63, w = t >> 6;
    if (lane == 0) red[w] = m;
    __syncthreads();
    m = fmaxf(fmaxf(red[0], red[1]), fmaxf(red[2], red[3]));
    __syncthreads();
    float s = 0.f;
#pragma unroll
    for (int i = 0; i < 16; ++i) {
        v[i] = __expf(v[i] - m);
        s += v[i];
    }
#pragma unroll
    for (int off = 32; off; off >>= 1) s += __shfl_xor(s, off, 64);
    if (lane == 0) red[w] = s;
    __syncthreads();
    s = red[0] + red[1] + red[2] + red[3];
    float inv = 1.0f / s;
#pragma unroll
    for (int i = 0; i < 16; ++i) Pr[t + i * 256] = f2bf(v[i] * inv);
}

// ---------------------------------------------------------------------------
extern "C" void kernel_launch(void* const* d_in, const int* in_sizes, int n_in,
                              void* d_out, int out_size, void* d_ws, size_t ws_size,
                              hipStream_t stream)
{
    const float* x     = (const float*)d_in[0];
    const float* gn_w  = (const float*)d_in[1];
    const float* gn_b  = (const float*)d_in[2];
    const float* qkv_w = (const float*)d_in[3];
    const float* qkv_b = (const float*)d_in[4];
    const float* out_w = (const float*)d_in[5];
    const float* out_b = (const float*)d_in[6];
    float* out = (float*)d_out;

    const size_t bnc = (size_t)NN * NC;          // 2,097,152 per batch
    char* w = (char*)d_ws;
    float* ss = (float*)w;                 w += 16384;
    unsigned short* wq = (unsigned short*)w; w += (size_t)1536 * 512 * 2;
    unsigned short* wo = (unsigned short*)w; w += (size_t)512 * 512 * 2;
    unsigned short* ht = (unsigned short*)w; w += NB * bnc * 2;   // (b,n,c)
    unsigned short* qt = (unsigned short*)w; w += NB * bnc * 2;   // (b,n,c)
    unsigned short* kt = (unsigned short*)w; w += NB * bnc * 2;   // (b,n,c)
    unsigned short* vt = (unsigned short*)w; w += NB * bnc * 2;   // (b,c,n)
    unsigned short* Ob = (unsigned short*)w; w += NB * bnc * 2;   // (b,n,c)
    float* S          = (float*)w;          w += (size_t)NN * NN * 4;  // 1 batch
    unsigned short* P  = (unsigned short*)w; w += (size_t)NN * NN * 2; // 1 batch

    gn_stats_kernel<<<NB * 32, 256, 0, stream>>>(x, gn_w, gn_b, ss);
    wconv_kernel<<<(1536 * 512 + 512 * 512) / 256, 256, 0, stream>>>(qkv_w, out_w, wq, wo);
    htnorm_kernel<<<dim3(NN / 32, NC / 32, NB), 256, 0, stream>>>(x, ss, ht);

    // q/k: C[p,o] = ht · wqk^T
    mfma_gemm<0><<<dim3(1024 / 128, NN / 128, NB), 256, 0, stream>>>(
        ht, wq, qkv_b, nullptr, nullptr, qt, kt);
    // v: C[c,p] = wv · ht^T
    mfma_gemm<1><<<dim3(NN / 128, 512 / 128, NB), 256, 0, stream>>>(
        wq + (size_t)1024 * 512, ht, qkv_b, nullptr, nullptr, vt, nullptr);

    for (int b = 0; b < NB; ++b) {
        mfma_gemm<2><<<dim3(NN / 128, NN / 128, 1), 256, 0, stream>>>(
            qt + (size_t)b * bnc, kt + (size_t)b * bnc, nullptr, nullptr, S, nullptr, nullptr);
        softmax_kernel<<<NN, 256, 0, stream>>>(S, P);
        mfma_gemm<3><<<dim3(512 / 128, NN / 128, 1), 256, 0, stream>>>(
            P, vt + (size_t)b * bnc, nullptr, nullptr, nullptr, Ob + (size_t)b * bnc, nullptr);
    }

    mfma_gemm<4><<<dim3(NN / 128, 512 / 128, NB), 256, 0, stream>>>(
        wo, Ob, out_b, x, out, nullptr, nullptr);
}

// Round 3
// 569.362 us; speedup vs baseline: 5.2258x; 1.3255x over previous
//
#include <hip/hip_runtime.h>
#include <cmath>

// b=4, c=512, n=4096, groups=32 (16 ch/group)
#define NB 4
#define NC 512
#define NN 4096
#define ATTN_SCALE 0.04419417382415922f  // 512^-0.5

typedef __bf16 bf16x8 __attribute__((ext_vector_type(8)));
typedef float floatx4 __attribute__((ext_vector_type(4)));

__device__ __forceinline__ unsigned short f2bf(float f) {
    union { float f; unsigned int u; } v; v.f = f;
    return (unsigned short)((v.u + 0x7fffu + ((v.u >> 16) & 1u)) >> 16);
}
__device__ __forceinline__ float bf2f(unsigned short u) {
    union { unsigned int u; float f; } v; v.u = ((unsigned int)u) << 16;
    return v.f;
}

__device__ __forceinline__ void gload_lds16(const unsigned short* gp, unsigned short* lp) {
    __builtin_amdgcn_global_load_lds(
        (const __attribute__((address_space(1))) void*)gp,
        (__attribute__((address_space(3))) void*)lp, 16, 0, 0);
}

// ---------------------------------------------------------------------------
// Kernel 1a: GroupNorm partial sums. 1024 blocks = (b,g) x 8 slices.
// ---------------------------------------------------------------------------
__global__ __launch_bounds__(256) void gn_partial_kernel(
    const float* __restrict__ x, float* __restrict__ part)
{
    int blk = blockIdx.x;
    int bg = blk >> 3, sub = blk & 7;
    const float4* xv = (const float4*)(x + (size_t)bg * 16 * NN + (size_t)sub * 8192);
    float s1 = 0.f, s2 = 0.f;
#pragma unroll
    for (int i = 0; i < 8; ++i) {
        float4 v = xv[threadIdx.x + i * 256];
        s1 += v.x + v.y + v.z + v.w;
        s2 += v.x * v.x + v.y * v.y + v.z * v.z + v.w * v.w;
    }
#pragma unroll
    for (int off = 32; off; off >>= 1) {
        s1 += __shfl_xor(s1, off, 64);
        s2 += __shfl_xor(s2, off, 64);
    }
    __shared__ float r1[4], r2[4];
    int lane = threadIdx.x & 63, w = threadIdx.x >> 6;
    if (lane == 0) { r1[w] = s1; r2[w] = s2; }
    __syncthreads();
    if (threadIdx.x == 0) {
        part[blk * 2]     = r1[0] + r1[1] + r1[2] + r1[3];
        part[blk * 2 + 1] = r2[0] + r2[1] + r2[2] + r2[3];
    }
}

// Kernel 1b: finalize -> per-channel scale/shift
__global__ __launch_bounds__(128) void gn_final_kernel(
    const float* __restrict__ part, const float* __restrict__ gw,
    const float* __restrict__ gb, float* __restrict__ ss)
{
    int tg = threadIdx.x;            // 0..127 = b*32+g
    int b = tg >> 5, g = tg & 31;
    float s1 = 0.f, s2 = 0.f;
#pragma unroll
    for (int s = 0; s < 8; ++s) {
        s1 += part[(tg * 8 + s) * 2];
        s2 += part[(tg * 8 + s) * 2 + 1];
    }
    float mean = s1 * (1.0f / 65536.0f);
    float var  = s2 * (1.0f / 65536.0f) - mean * mean;
    float rstd = rsqrtf(var + 1e-5f);
#pragma unroll
    for (int i = 0; i < 16; ++i) {
        int c = g * 16 + i;
        float sc = rstd * gw[c];
        ss[b * NC + c] = sc;
        ss[2048 + b * NC + c] = gb[c] - mean * sc;
    }
}

// ---------------------------------------------------------------------------
// Kernel 2: convert weights fp32 -> bf16
// ---------------------------------------------------------------------------
__global__ __launch_bounds__(256) void wconv_kernel(
    const float* __restrict__ qkv_w, const float* __restrict__ out_w,
    unsigned short* __restrict__ wq, unsigned short* __restrict__ wo)
{
    int i = blockIdx.x * 256 + threadIdx.x;
    const int NQ = 1536 * 512;
    if (i < NQ) wq[i] = f2bf(qkv_w[i]);
    else        wo[i - NQ] = f2bf(out_w[i - NQ]);
}

// ---------------------------------------------------------------------------
// Kernel 3: normalize + transpose: x (b,c,n) fp32 -> h_t (b,n,c) bf16
// ---------------------------------------------------------------------------
__global__ __launch_bounds__(256) void htnorm_kernel(
    const float* __restrict__ x, const float* __restrict__ ss,
    unsigned short* __restrict__ ht)
{
    int b = blockIdx.z;
    int c0 = blockIdx.y * 32, n0 = blockIdx.x * 32;
    __shared__ float T[32][33];
    int tx = threadIdx.x & 31, ty = threadIdx.x >> 5;   // ty 0..7
    const float* xb = x + ((size_t)b * NC + c0) * NN;
    const float* sc = ss + b * NC + c0;
    const float* sh = ss + 2048 + b * NC + c0;
#pragma unroll
    for (int i = 0; i < 4; ++i) {
        int c = ty + i * 8;
        T[c][tx] = xb[(size_t)c * NN + n0 + tx] * sc[c] + sh[c];
    }
    __syncthreads();
    unsigned short* hb = ht + ((size_t)b * NN + n0) * NC + c0;
#pragma unroll
    for (int i = 0; i < 4; ++i) {
        int n = ty + i * 8;
        hb[(size_t)n * NC + tx] = f2bf(T[tx][n]);
    }
}

// ---------------------------------------------------------------------------
// MFMA NT GEMM: C[m,n] = sum_k A[m,k]*B[n,k], BMxBN block tile, BK=32.
// MODE 0: qkv q/k   M=4096 N=1024 K=512  A=ht(+z) B=wqk    -> qt(*scale)/kt +bias
// MODE 1: qkv v     M=512  N=4096 K=512  A=wv     B=ht(+z) -> vt (c,p) bf16 +bias
// MODE 2: QK^T      M=4096 N=4096 K=512  A=qt     B=kt     -> S bf16
// MODE 3: PV        M=4096 N=512  K=4096 A=P      B=vt     -> O (p,c) bf16
// MODE 4: out proj  M=512  N=4096 K=512  A=wo     B=O(+z)  -> out fp32 +bias+res
// ---------------------------------------------------------------------------
template<int MODE, int BM, int BN>
__global__ __launch_bounds__(256) void mfma_gemm(
    const unsigned short* __restrict__ Abase,
    const unsigned short* __restrict__ Bbase,
    const float* __restrict__ e0, const float* __restrict__ e1,
    float* __restrict__ outf,
    unsigned short* __restrict__ ob0, unsigned short* __restrict__ ob1)
{
    constexpr int K = (MODE == 3) ? 4096 : 512;
    constexpr int FI = BM / 32;       // frag rows per wave
    constexpr int FJ = BN / 32;       // frag cols per wave
    const int z = blockIdx.z;
    const size_t bnc = (size_t)NN * NC;

    const unsigned short* A;
    const unsigned short* B;
    if constexpr (MODE == 0)      { A = Abase + (size_t)z * bnc; B = Bbase; }
    else if constexpr (MODE == 1) { A = Abase; B = Bbase + (size_t)z * bnc; }
    else if constexpr (MODE == 4) { A = Abase; B = Bbase + (size_t)z * bnc; }
    else                          { A = Abase; B = Bbase; }   // MODE 2/3 pre-offset

    const int m0 = blockIdx.y * BM;
    const int n0 = blockIdx.x * BN;

    __shared__ __attribute__((aligned(16))) unsigned short As[BM * 32];
    __shared__ __attribute__((aligned(16))) unsigned short Bs[BN * 32];

    const int t = threadIdx.x;
    const int lane = t & 63;
    const int w = t >> 6;
    const int wr = w >> 1, wc = w & 1;

    const int sr = w * 16 + (lane >> 2);       // staging row within 64-row slab
    const int sc8 = (lane & 3) * 8;            // element offset within 32
    const int lds_elem = w * 512;

    floatx4 acc[FI][FJ] = {};

    for (int k0 = 0; k0 < K; k0 += 32) {
#pragma unroll
        for (int s = 0; s < BM / 64; ++s)
            gload_lds16(A + (size_t)(m0 + s * 64 + sr) * K + k0 + sc8,
                        As + s * 2048 + lds_elem);
#pragma unroll
        for (int s = 0; s < BN / 64; ++s)
            gload_lds16(B + (size_t)(n0 + s * 64 + sr) * K + k0 + sc8,
                        Bs + s * 2048 + lds_elem);
        __syncthreads();

        bf16x8 af[FI], bfr[FJ];
        const unsigned short* Ab = As + ((wr * (BM / 2) + (lane & 15)) * 32) + (lane >> 4) * 8;
        const unsigned short* Bb = Bs + ((wc * (BN / 2) + (lane & 15)) * 32) + (lane >> 4) * 8;
#pragma unroll
        for (int i = 0; i < FI; ++i) af[i]  = *(const bf16x8*)(Ab + i * 16 * 32);
#pragma unroll
        for (int j = 0; j < FJ; ++j) bfr[j] = *(const bf16x8*)(Bb + j * 16 * 32);
#pragma unroll
        for (int i = 0; i < FI; ++i)
#pragma unroll
            for (int j = 0; j < FJ; ++j)
                acc[i][j] = __builtin_amdgcn_mfma_f32_16x16x32_bf16(
                    af[i], bfr[j], acc[i][j], 0, 0, 0);
        __syncthreads();
    }

    // Epilogue. C/D: col = lane&15, row = (lane>>4)*4 + reg
    const int fr = lane >> 4;
    const int fc = lane & 15;
#pragma unroll
    for (int i = 0; i < FI; ++i) {
#pragma unroll
        for (int j = 0; j < FJ; ++j) {
            int n = n0 + wc * (BN / 2) + j * 16 + fc;
            int mbase = m0 + wr * (BM / 2) + i * 16 + fr * 4;
#pragma unroll
            for (int r = 0; r < 4; ++r) {
                int m = mbase + r;
                float val = acc[i][j][r];
                if constexpr (MODE == 0) {
                    val += e0[n];   // qkv bias, o = n in [0,1024)
                    if (n < 512) ob0[((size_t)z * NN + m) * NC + n] = f2bf(val * ATTN_SCALE);
                    else         ob1[((size_t)z * NN + m) * NC + (n - 512)] = f2bf(val);
                } else if constexpr (MODE == 1) {
                    val += e0[1024 + m];   // v bias, channel = m
                    ob0[((size_t)z * NC + m) * NN + n] = f2bf(val);
                } else if constexpr (MODE == 2) {
                    ob0[(size_t)m * NN + n] = f2bf(val);   // scale already in q
                } else if constexpr (MODE == 3) {
                    ob0[(size_t)m * NC + n] = f2bf(val);
                } else {   // MODE 4
                    size_t idx = ((size_t)z * NC + m) * NN + n;
                    outf[idx] = val + e0[m] + e1[idx];
                }
            }
        }
    }
}

// ---------------------------------------------------------------------------
// Softmax in-place on bf16 S rows: 16 contiguous elements per thread.
// ---------------------------------------------------------------------------
__global__ __launch_bounds__(256) void softmax_kernel(unsigned short* __restrict__ SP)
{
    int row = blockIdx.x;
    unsigned short* Pr = SP + (size_t)row * NN;
    int t = threadIdx.x;
    union { uint4 q[2]; unsigned short s[16]; } u;
    u.q[0] = ((const uint4*)Pr)[t * 2];
    u.q[1] = ((const uint4*)Pr)[t * 2 + 1];
    float v[16];
    float m = -INFINITY;
#pragma unroll
    for (int i = 0; i < 16; ++i) {
        v[i] = bf2f(u.s[i]);
        m = fmaxf(m, v[i]);
    }
#pragma unroll
    for (int off = 32; off; off >>= 1) m = fmaxf(m, __shfl_xor(m, off, 64));
    __shared__ float red[4];
    int lane = t & 63, w = t >> 6;
    if (lane == 0) red[w] = m;
    __syncthreads();
    m = fmaxf(fmaxf(red[0], red[1]), fmaxf(red[2], red[3]));
    __syncthreads();
    float s = 0.f;
#pragma unroll
    for (int i = 0; i < 16; ++i) {
        v[i] = __expf(v[i] - m);
        s += v[i];
    }
#pragma unroll
    for (int off = 32; off; off >>= 1) s += __shfl_xor(s, off, 64);
    if (lane == 0) red[w] = s;
    __syncthreads();
    s = red[0] + red[1] + red[2] + red[3];
    float inv = 1.0f / s;
#pragma unroll
    for (int i = 0; i < 16; ++i) u.s[i] = f2bf(v[i] * inv);
    ((uint4*)Pr)[t * 2]     = u.q[0];
    ((uint4*)Pr)[t * 2 + 1] = u.q[1];
}

// ---------------------------------------------------------------------------
extern "C" void kernel_launch(void* const* d_in, const int* in_sizes, int n_in,
                              void* d_out, int out_size, void* d_ws, size_t ws_size,
                              hipStream_t stream)
{
    const float* x     = (const float*)d_in[0];
    const float* gn_w  = (const float*)d_in[1];
    const float* gn_b  = (const float*)d_in[2];
    const float* qkv_w = (const float*)d_in[3];
    const float* qkv_b = (const float*)d_in[4];
    const float* out_w = (const float*)d_in[5];
    const float* out_b = (const float*)d_in[6];
    float* out = (float*)d_out;

    const size_t bnc = (size_t)NN * NC;          // 2,097,152 per batch
    char* w = (char*)d_ws;
    float* ss   = (float*)w;                 w += 16384;
    float* part = (float*)w;                 w += 2048 * 4;
    unsigned short* wq = (unsigned short*)w; w += (size_t)1536 * 512 * 2;
    unsigned short* wo = (unsigned short*)w; w += (size_t)512 * 512 * 2;
    unsigned short* ht = (unsigned short*)w; w += NB * bnc * 2;   // (b,n,c)
    unsigned short* qt = (unsigned short*)w; w += NB * bnc * 2;   // (b,n,c), pre-scaled
    unsigned short* kt = (unsigned short*)w; w += NB * bnc * 2;   // (b,n,c)
    unsigned short* vt = (unsigned short*)w; w += NB * bnc * 2;   // (b,c,n)
    unsigned short* Ob = (unsigned short*)w; w += NB * bnc * 2;   // (b,n,c)
    unsigned short* SP = (unsigned short*)w; w += (size_t)NN * NN * 2; // 1 batch, in-place

    gn_partial_kernel<<<1024, 256, 0, stream>>>(x, part);
    gn_final_kernel<<<1, 128, 0, stream>>>(part, gn_w, gn_b, ss);
    wconv_kernel<<<(1536 * 512 + 512 * 512) / 256, 256, 0, stream>>>(qkv_w, out_w, wq, wo);
    htnorm_kernel<<<dim3(NN / 32, NC / 32, NB), 256, 0, stream>>>(x, ss, ht);

    // q/k: C[p,o] = ht · wqk^T
    mfma_gemm<0, 128, 128><<<dim3(1024 / 128, NN / 128, NB), 256, 0, stream>>>(
        ht, wq, qkv_b, nullptr, nullptr, qt, kt);
    // v: C[c,p] = wv · ht^T
    mfma_gemm<1, 128, 128><<<dim3(NN / 128, 512 / 128, NB), 256, 0, stream>>>(
        wq + (size_t)1024 * 512, ht, qkv_b, nullptr, nullptr, vt, nullptr);

    for (int b = 0; b < NB; ++b) {
        mfma_gemm<2, 128, 128><<<dim3(NN / 128, NN / 128, 1), 256, 0, stream>>>(
            qt + (size_t)b * bnc, kt + (size_t)b * bnc, nullptr, nullptr,
            nullptr, SP, nullptr);
        softmax_kernel<<<NN, 256, 0, stream>>>(SP);
        mfma_gemm<3, 128, 64><<<dim3(512 / 64, NN / 128, 1), 256, 0, stream>>>(
            SP, vt + (size_t)b * bnc, nullptr, nullptr,
            nullptr, Ob + (size_t)b * bnc, nullptr);
    }

    mfma_gemm<4, 128, 128><<<dim3(NN / 128, 512 / 128, NB), 256, 0, stream>>>(
        wo, Ob, out_b, x, out, nullptr, nullptr);
}

// Round 4
// 427.699 us; speedup vs baseline: 6.9567x; 1.3312x over previous
//
#include <hip/hip_runtime.h>
#include <cmath>

// b=4, c=512, n=4096, groups=32 (16 ch/group)
#define NB 4
#define NC 512
#define NN 4096
#define ATTN_SCALE 0.04419417382415922f  // 512^-0.5

typedef __bf16 bf16x8 __attribute__((ext_vector_type(8)));
typedef float floatx4 __attribute__((ext_vector_type(4)));

__device__ __forceinline__ unsigned short f2bf(float f) {
    union { float f; unsigned int u; } v; v.f = f;
    return (unsigned short)((v.u + 0x7fffu + ((v.u >> 16) & 1u)) >> 16);
}
__device__ __forceinline__ float bf2f(unsigned short u) {
    union { unsigned int u; float f; } v; v.u = ((unsigned int)u) << 16;
    return v.f;
}

__device__ __forceinline__ void gload_lds16(const unsigned short* gp, unsigned short* lp) {
    __builtin_amdgcn_global_load_lds(
        (const __attribute__((address_space(1))) void*)gp,
        (__attribute__((address_space(3))) void*)lp, 16, 0, 0);
}

// ---------------------------------------------------------------------------
// Kernel 1a: GroupNorm partial sums. 1024 blocks = (b,g) x 8 slices.
// ---------------------------------------------------------------------------
__global__ __launch_bounds__(256) void gn_partial_kernel(
    const float* __restrict__ x, float* __restrict__ part)
{
    int blk = blockIdx.x;
    int bg = blk >> 3, sub = blk & 7;
    const float4* xv = (const float4*)(x + (size_t)bg * 16 * NN + (size_t)sub * 8192);
    float s1 = 0.f, s2 = 0.f;
#pragma unroll
    for (int i = 0; i < 8; ++i) {
        float4 v = xv[threadIdx.x + i * 256];
        s1 += v.x + v.y + v.z + v.w;
        s2 += v.x * v.x + v.y * v.y + v.z * v.z + v.w * v.w;
    }
#pragma unroll
    for (int off = 32; off; off >>= 1) {
        s1 += __shfl_xor(s1, off, 64);
        s2 += __shfl_xor(s2, off, 64);
    }
    __shared__ float r1[4], r2[4];
    int lane = threadIdx.x & 63, w = threadIdx.x >> 6;
    if (lane == 0) { r1[w] = s1; r2[w] = s2; }
    __syncthreads();
    if (threadIdx.x == 0) {
        part[blk * 2]     = r1[0] + r1[1] + r1[2] + r1[3];
        part[blk * 2 + 1] = r2[0] + r2[1] + r2[2] + r2[3];
    }
}

// Kernel 1b: finalize -> per-channel scale/shift
__global__ __launch_bounds__(128) void gn_final_kernel(
    const float* __restrict__ part, const float* __restrict__ gw,
    const float* __restrict__ gb, float* __restrict__ ss)
{
    int tg = threadIdx.x;            // 0..127 = b*32+g
    int b = tg >> 5, g = tg & 31;
    float s1 = 0.f, s2 = 0.f;
#pragma unroll
    for (int s = 0; s < 8; ++s) {
        s1 += part[(tg * 8 + s) * 2];
        s2 += part[(tg * 8 + s) * 2 + 1];
    }
    float mean = s1 * (1.0f / 65536.0f);
    float var  = s2 * (1.0f / 65536.0f) - mean * mean;
    float rstd = rsqrtf(var + 1e-5f);
#pragma unroll
    for (int i = 0; i < 16; ++i) {
        int c = g * 16 + i;
        float sc = rstd * gw[c];
        ss[b * NC + c] = sc;
        ss[2048 + b * NC + c] = gb[c] - mean * sc;
    }
}

// ---------------------------------------------------------------------------
// Kernel 2: convert weights fp32 -> bf16
// ---------------------------------------------------------------------------
__global__ __launch_bounds__(256) void wconv_kernel(
    const float* __restrict__ qkv_w, const float* __restrict__ out_w,
    unsigned short* __restrict__ wq, unsigned short* __restrict__ wo)
{
    int i = blockIdx.x * 256 + threadIdx.x;
    const int NQ = 1536 * 512;
    if (i < NQ) wq[i] = f2bf(qkv_w[i]);
    else        wo[i - NQ] = f2bf(out_w[i - NQ]);
}

// ---------------------------------------------------------------------------
// Kernel 3: normalize + transpose: x (b,c,n) fp32 -> h_t (b,n,c) bf16
// ---------------------------------------------------------------------------
__global__ __launch_bounds__(256) void htnorm_kernel(
    const float* __restrict__ x, const float* __restrict__ ss,
    unsigned short* __restrict__ ht)
{
    int b = blockIdx.z;
    int c0 = blockIdx.y * 32, n0 = blockIdx.x * 32;
    __shared__ float T[32][33];
    int tx = threadIdx.x & 31, ty = threadIdx.x >> 5;   // ty 0..7
    const float* xb = x + ((size_t)b * NC + c0) * NN;
    const float* sc = ss + b * NC + c0;
    const float* sh = ss + 2048 + b * NC + c0;
#pragma unroll
    for (int i = 0; i < 4; ++i) {
        int c = ty + i * 8;
        T[c][tx] = xb[(size_t)c * NN + n0 + tx] * sc[c] + sh[c];
    }
    __syncthreads();
    unsigned short* hb = ht + ((size_t)b * NN + n0) * NC + c0;
#pragma unroll
    for (int i = 0; i < 4; ++i) {
        int n = ty + i * 8;
        hb[(size_t)n * NC + tx] = f2bf(T[tx][n]);
    }
}

// ---------------------------------------------------------------------------
// MFMA NT GEMM: C[m,n] = sum_k A[m,k]*B[n,k], BMxBN block tile, BK=32.
// MODE 0: qkv q/k   M=4096 N=1024 K=512  A=ht(+z) B=wqk    -> qt(*scale)/kt +bias
// MODE 1: qkv v     M=512  N=4096 K=512  A=wv     B=ht(+z) -> vt (c,p) bf16 +bias
// MODE 2: QK^T      M=4096 N=4096 K=512  A=qt(+z) B=kt(+z) -> SP bf16 (+z)
// MODE 3: PV        M=4096 N=512  K=4096 A=SP(+z) B=vt(+z) -> Ob (p,c) bf16 (+z)
// MODE 4: out proj  M=512  N=4096 K=512  A=wo     B=Ob(+z) -> out fp32 +bias+res
// ---------------------------------------------------------------------------
template<int MODE, int BM, int BN>
__global__ __launch_bounds__(256) void mfma_gemm(
    const unsigned short* __restrict__ Abase,
    const unsigned short* __restrict__ Bbase,
    const float* __restrict__ e0, const float* __restrict__ e1,
    float* __restrict__ outf,
    unsigned short* __restrict__ ob0, unsigned short* __restrict__ ob1)
{
    constexpr int K = (MODE == 3) ? 4096 : 512;
    constexpr int FI = BM / 32;       // frag rows per wave
    constexpr int FJ = BN / 32;       // frag cols per wave
    const int z = blockIdx.z;
    const size_t bnc = (size_t)NN * NC;
    const size_t bss = (size_t)NN * NN;

    const unsigned short* A;
    const unsigned short* B;
    if constexpr (MODE == 0)      { A = Abase + (size_t)z * bnc; B = Bbase; }
    else if constexpr (MODE == 1) { A = Abase; B = Bbase + (size_t)z * bnc; }
    else if constexpr (MODE == 2) { A = Abase + (size_t)z * bnc; B = Bbase + (size_t)z * bnc; }
    else if constexpr (MODE == 3) { A = Abase + (size_t)z * bss; B = Bbase + (size_t)z * bnc; }
    else                          { A = Abase; B = Bbase + (size_t)z * bnc; }

    const int m0 = blockIdx.y * BM;
    const int n0 = blockIdx.x * BN;

    __shared__ __attribute__((aligned(16))) unsigned short As[BM * 32];
    __shared__ __attribute__((aligned(16))) unsigned short Bs[BN * 32];

    const int t = threadIdx.x;
    const int lane = t & 63;
    const int w = t >> 6;
    const int wr = w >> 1, wc = w & 1;

    const int sr = w * 16 + (lane >> 2);       // staging row within 64-row slab
    const int sc8 = (lane & 3) * 8;            // element offset within 32
    const int lds_elem = w * 512;

    floatx4 acc[FI][FJ] = {};

    for (int k0 = 0; k0 < K; k0 += 32) {
#pragma unroll
        for (int s = 0; s < BM / 64; ++s)
            gload_lds16(A + (size_t)(m0 + s * 64 + sr) * K + k0 + sc8,
                        As + s * 2048 + lds_elem);
#pragma unroll
        for (int s = 0; s < BN / 64; ++s)
            gload_lds16(B + (size_t)(n0 + s * 64 + sr) * K + k0 + sc8,
                        Bs + s * 2048 + lds_elem);
        __syncthreads();

        bf16x8 af[FI], bfr[FJ];
        const unsigned short* Ab = As + ((wr * (BM / 2) + (lane & 15)) * 32) + (lane >> 4) * 8;
        const unsigned short* Bb = Bs + ((wc * (BN / 2) + (lane & 15)) * 32) + (lane >> 4) * 8;
#pragma unroll
        for (int i = 0; i < FI; ++i) af[i]  = *(const bf16x8*)(Ab + i * 16 * 32);
#pragma unroll
        for (int j = 0; j < FJ; ++j) bfr[j] = *(const bf16x8*)(Bb + j * 16 * 32);
#pragma unroll
        for (int i = 0; i < FI; ++i)
#pragma unroll
            for (int j = 0; j < FJ; ++j)
                acc[i][j] = __builtin_amdgcn_mfma_f32_16x16x32_bf16(
                    af[i], bfr[j], acc[i][j], 0, 0, 0);
        __syncthreads();
    }

    // Epilogue. C/D: col = lane&15, row = (lane>>4)*4 + reg
    const int fr = lane >> 4;
    const int fc = lane & 15;
#pragma unroll
    for (int i = 0; i < FI; ++i) {
#pragma unroll
        for (int j = 0; j < FJ; ++j) {
            int n = n0 + wc * (BN / 2) + j * 16 + fc;
            int mbase = m0 + wr * (BM / 2) + i * 16 + fr * 4;
#pragma unroll
            for (int r = 0; r < 4; ++r) {
                int m = mbase + r;
                float val = acc[i][j][r];
                if constexpr (MODE == 0) {
                    val += e0[n];   // qkv bias, o = n in [0,1024)
                    if (n < 512) ob0[((size_t)z * NN + m) * NC + n] = f2bf(val * ATTN_SCALE);
                    else         ob1[((size_t)z * NN + m) * NC + (n - 512)] = f2bf(val);
                } else if constexpr (MODE == 1) {
                    val += e0[1024 + m];   // v bias, channel = m
                    ob0[((size_t)z * NC + m) * NN + n] = f2bf(val);
                } else if constexpr (MODE == 2) {
                    ob0[(size_t)z * bss + (size_t)m * NN + n] = f2bf(val);
                } else if constexpr (MODE == 3) {
                    ob0[(size_t)z * bnc + (size_t)m * NC + n] = f2bf(val);
                } else {   // MODE 4
                    size_t idx = ((size_t)z * NC + m) * NN + n;
                    outf[idx] = val + e0[m] + e1[idx];
                }
            }
        }
    }
}

// ---------------------------------------------------------------------------
// Softmax in-place on bf16 S rows: 16 contiguous elements per thread.
// grid = (row, batch)
// ---------------------------------------------------------------------------
__global__ __launch_bounds__(256) void softmax_kernel(unsigned short* __restrict__ SP)
{
    unsigned short* Pr = SP + ((size_t)blockIdx.y * NN + blockIdx.x) * NN;
    int t = threadIdx.x;
    union { uint4 q[2]; unsigned short s[16]; } u;
    u.q[0] = ((const uint4*)Pr)[t * 2];
    u.q[1] = ((const uint4*)Pr)[t * 2 + 1];
    float v[16];
    float m = -INFINITY;
#pragma unroll
    for (int i = 0; i < 16; ++i) {
        v[i] = bf2f(u.s[i]);
        m = fmaxf(m, v[i]);
    }
#pragma unroll
    for (int off = 32; off; off >>= 1) m = fmaxf(m, __shfl_xor(m, off, 64));
    __shared__ float red[4];
    int lane = t & 63, w = t >> 6;
    if (lane == 0) red[w] = m;
    __syncthreads();
    m = fmaxf(fmaxf(red[0], red[1]), fmaxf(red[2], red[3]));
    __syncthreads();
    float s = 0.f;
#pragma unroll
    for (int i = 0; i < 16; ++i) {
        v[i] = __expf(v[i] - m);
        s += v[i];
    }
#pragma unroll
    for (int off = 32; off; off >>= 1) s += __shfl_xor(s, off, 64);
    if (lane == 0) red[w] = s;
    __syncthreads();
    s = red[0] + red[1] + red[2] + red[3];
    float inv = 1.0f / s;
#pragma unroll
    for (int i = 0; i < 16; ++i) u.s[i] = f2bf(v[i] * inv);
    ((uint4*)Pr)[t * 2]     = u.q[0];
    ((uint4*)Pr)[t * 2 + 1] = u.q[1];
}

// ---------------------------------------------------------------------------
extern "C" void kernel_launch(void* const* d_in, const int* in_sizes, int n_in,
                              void* d_out, int out_size, void* d_ws, size_t ws_size,
                              hipStream_t stream)
{
    const float* x     = (const float*)d_in[0];
    const float* gn_w  = (const float*)d_in[1];
    const float* gn_b  = (const float*)d_in[2];
    const float* qkv_w = (const float*)d_in[3];
    const float* qkv_b = (const float*)d_in[4];
    const float* out_w = (const float*)d_in[5];
    const float* out_b = (const float*)d_in[6];
    float* out = (float*)d_out;

    const size_t bnc = (size_t)NN * NC;          // 2,097,152 per batch
    char* w = (char*)d_ws;
    float* ss   = (float*)w;                 w += 16384;
    float* part = (float*)w;                 w += 8192;
    unsigned short* wq = (unsigned short*)w; w += (size_t)1536 * 512 * 2;
    unsigned short* wo = (unsigned short*)w; w += (size_t)512 * 512 * 2;
    unsigned short* qt = (unsigned short*)w; w += NB * bnc * 2;   // (b,n,c) pre-scaled
    unsigned short* kt = (unsigned short*)w; w += NB * bnc * 2;   // (b,n,c)
    unsigned short* vt = (unsigned short*)w; w += NB * bnc * 2;   // (b,c,n)
    unsigned short* SP = (unsigned short*)w; w += (size_t)NB * NN * NN * 2; // 128 MB
    // Aliases (lifetime-disjoint):
    unsigned short* ht = SP;   // ht (b,n,c) dead before MODE 2 writes SP
    unsigned short* Ob = qt;   // Ob (b,n,c) written after qt last read (MODE 2)

    gn_partial_kernel<<<1024, 256, 0, stream>>>(x, part);
    gn_final_kernel<<<1, 128, 0, stream>>>(part, gn_w, gn_b, ss);
    wconv_kernel<<<(1536 * 512 + 512 * 512) / 256, 256, 0, stream>>>(qkv_w, out_w, wq, wo);
    htnorm_kernel<<<dim3(NN / 32, NC / 32, NB), 256, 0, stream>>>(x, ss, ht);

    // q/k: C[p,o] = ht · wqk^T   (q pre-scaled by ATTN_SCALE)
    mfma_gemm<0, 128, 128><<<dim3(1024 / 128, NN / 128, NB), 256, 0, stream>>>(
        ht, wq, qkv_b, nullptr, nullptr, qt, kt);
    // v: C[c,p] = wv · ht^T
    mfma_gemm<1, 128, 128><<<dim3(NN / 128, 512 / 128, NB), 256, 0, stream>>>(
        wq + (size_t)1024 * 512, ht, qkv_b, nullptr, nullptr, vt, nullptr);

    // QK^T, all batches, one dispatch
    mfma_gemm<2, 128, 128><<<dim3(NN / 128, NN / 128, NB), 256, 0, stream>>>(
        qt, kt, nullptr, nullptr, nullptr, SP, nullptr);
    // softmax, all batches
    softmax_kernel<<<dim3(NN, NB), 256, 0, stream>>>(SP);
    // PV, all batches
    mfma_gemm<3, 128, 128><<<dim3(512 / 128, NN / 128, NB), 256, 0, stream>>>(
        SP, vt, nullptr, nullptr, nullptr, Ob, nullptr);

    // out projection + bias + residual
    mfma_gemm<4, 128, 128><<<dim3(NN / 128, 512 / 128, NB), 256, 0, stream>>>(
        wo, Ob, out_b, x, out, nullptr, nullptr);
}

// Round 5
// 419.616 us; speedup vs baseline: 7.0907x; 1.0193x over previous
//
#include <hip/hip_runtime.h>
#include <cmath>

// b=4, c=512, n=4096, groups=32 (16 ch/group)
#define NB 4
#define NC 512
#define NN 4096
#define ATTN_SCALE 0.04419417382415922f  // 512^-0.5

typedef __bf16 bf16x8 __attribute__((ext_vector_type(8)));
typedef float floatx4 __attribute__((ext_vector_type(4)));

__device__ __forceinline__ unsigned short f2bf(float f) {
    union { float f; unsigned int u; } v; v.f = f;
    return (unsigned short)((v.u + 0x7fffu + ((v.u >> 16) & 1u)) >> 16);
}
__device__ __forceinline__ float bf2f(unsigned short u) {
    union { unsigned int u; float f; } v; v.u = ((unsigned int)u) << 16;
    return v.f;
}

__device__ __forceinline__ void gload_lds16(const unsigned short* gp, unsigned short* lp) {
    __builtin_amdgcn_global_load_lds(
        (const __attribute__((address_space(1))) void*)gp,
        (__attribute__((address_space(3))) void*)lp, 16, 0, 0);
}

// ---------------------------------------------------------------------------
// Kernel 1a: GroupNorm partial sums. 1024 blocks = (b,g) x 8 slices.
// ---------------------------------------------------------------------------
__global__ __launch_bounds__(256) void gn_partial_kernel(
    const float* __restrict__ x, float* __restrict__ part)
{
    int blk = blockIdx.x;
    int bg = blk >> 3, sub = blk & 7;
    const float4* xv = (const float4*)(x + (size_t)bg * 16 * NN + (size_t)sub * 8192);
    float s1 = 0.f, s2 = 0.f;
#pragma unroll
    for (int i = 0; i < 8; ++i) {
        float4 v = xv[threadIdx.x + i * 256];
        s1 += v.x + v.y + v.z + v.w;
        s2 += v.x * v.x + v.y * v.y + v.z * v.z + v.w * v.w;
    }
#pragma unroll
    for (int off = 32; off; off >>= 1) {
        s1 += __shfl_xor(s1, off, 64);
        s2 += __shfl_xor(s2, off, 64);
    }
    __shared__ float r1[4], r2[4];
    int lane = threadIdx.x & 63, w = threadIdx.x >> 6;
    if (lane == 0) { r1[w] = s1; r2[w] = s2; }
    __syncthreads();
    if (threadIdx.x == 0) {
        part[blk * 2]     = r1[0] + r1[1] + r1[2] + r1[3];
        part[blk * 2 + 1] = r2[0] + r2[1] + r2[2] + r2[3];
    }
}

// Kernel 1b: finalize -> per-channel scale/shift
__global__ __launch_bounds__(128) void gn_final_kernel(
    const float* __restrict__ part, const float* __restrict__ gw,
    const float* __restrict__ gb, float* __restrict__ ss)
{
    int tg = threadIdx.x;            // 0..127 = b*32+g
    int b = tg >> 5, g = tg & 31;
    float s1 = 0.f, s2 = 0.f;
#pragma unroll
    for (int s = 0; s < 8; ++s) {
        s1 += part[(tg * 8 + s) * 2];
        s2 += part[(tg * 8 + s) * 2 + 1];
    }
    float mean = s1 * (1.0f / 65536.0f);
    float var  = s2 * (1.0f / 65536.0f) - mean * mean;
    float rstd = rsqrtf(var + 1e-5f);
#pragma unroll
    for (int i = 0; i < 16; ++i) {
        int c = g * 16 + i;
        float sc = rstd * gw[c];
        ss[b * NC + c] = sc;
        ss[2048 + b * NC + c] = gb[c] - mean * sc;
    }
}

// ---------------------------------------------------------------------------
// Kernel 2: convert weights fp32 -> bf16
// ---------------------------------------------------------------------------
__global__ __launch_bounds__(256) void wconv_kernel(
    const float* __restrict__ qkv_w, const float* __restrict__ out_w,
    unsigned short* __restrict__ wq, unsigned short* __restrict__ wo)
{
    int i = blockIdx.x * 256 + threadIdx.x;
    const int NQ = 1536 * 512;
    if (i < NQ) wq[i] = f2bf(qkv_w[i]);
    else        wo[i - NQ] = f2bf(out_w[i - NQ]);
}

// ---------------------------------------------------------------------------
// Kernel 3: normalize + transpose: x (b,c,n) fp32 -> h_t (b,n,c) bf16
// ---------------------------------------------------------------------------
__global__ __launch_bounds__(256) void htnorm_kernel(
    const float* __restrict__ x, const float* __restrict__ ss,
    unsigned short* __restrict__ ht)
{
    int b = blockIdx.z;
    int c0 = blockIdx.y * 32, n0 = blockIdx.x * 32;
    __shared__ float T[32][33];
    int tx = threadIdx.x & 31, ty = threadIdx.x >> 5;   // ty 0..7
    const float* xb = x + ((size_t)b * NC + c0) * NN;
    const float* sc = ss + b * NC + c0;
    const float* sh = ss + 2048 + b * NC + c0;
#pragma unroll
    for (int i = 0; i < 4; ++i) {
        int c = ty + i * 8;
        T[c][tx] = xb[(size_t)c * NN + n0 + tx] * sc[c] + sh[c];
    }
    __syncthreads();
    unsigned short* hb = ht + ((size_t)b * NN + n0) * NC + c0;
#pragma unroll
    for (int i = 0; i < 4; ++i) {
        int n = ty + i * 8;
        hb[(size_t)n * NC + tx] = f2bf(T[tx][n]);
    }
}

// ---------------------------------------------------------------------------
// MFMA NT GEMM: C[m,n] = sum_k A[m,k]*B[n,k], BMxBN block tile, BK=32.
// MODE 0: qkv q/k   M=4096 N=1024 K=512  A=ht(+z) B=wqk    -> qt(*scale)/kt +bias
// MODE 1: qkv v     M=512  N=4096 K=512  A=wv     B=ht(+z) -> vt (c,p) bf16 +bias
// MODE 2: QK^T      M=4096 N=4096 K=512  A=qt(+z) B=kt(+z) -> SP bf16 (+z)
// MODE 4: out proj  M=512  N=4096 K=512  A=wo     B=Ob(+z) -> out fp32 +bias+res
// ---------------------------------------------------------------------------
template<int MODE, int BM, int BN>
__global__ __launch_bounds__(256) void mfma_gemm(
    const unsigned short* __restrict__ Abase,
    const unsigned short* __restrict__ Bbase,
    const float* __restrict__ e0, const float* __restrict__ e1,
    float* __restrict__ outf,
    unsigned short* __restrict__ ob0, unsigned short* __restrict__ ob1)
{
    constexpr int K = 512;
    constexpr int FI = BM / 32;       // frag rows per wave
    constexpr int FJ = BN / 32;       // frag cols per wave
    const int z = blockIdx.z;
    const size_t bnc = (size_t)NN * NC;
    const size_t bss = (size_t)NN * NN;

    const unsigned short* A;
    const unsigned short* B;
    if constexpr (MODE == 0)      { A = Abase + (size_t)z * bnc; B = Bbase; }
    else if constexpr (MODE == 1) { A = Abase; B = Bbase + (size_t)z * bnc; }
    else if constexpr (MODE == 2) { A = Abase + (size_t)z * bnc; B = Bbase + (size_t)z * bnc; }
    else                          { A = Abase; B = Bbase + (size_t)z * bnc; }

    const int m0 = blockIdx.y * BM;
    const int n0 = blockIdx.x * BN;

    __shared__ __attribute__((aligned(16))) unsigned short As[BM * 32];
    __shared__ __attribute__((aligned(16))) unsigned short Bs[BN * 32];

    const int t = threadIdx.x;
    const int lane = t & 63;
    const int w = t >> 6;
    const int wr = w >> 1, wc = w & 1;

    const int sr = w * 16 + (lane >> 2);       // staging row within 64-row slab
    const int sc8 = (lane & 3) * 8;            // element offset within 32
    const int lds_elem = w * 512;

    floatx4 acc[FI][FJ] = {};

    for (int k0 = 0; k0 < K; k0 += 32) {
#pragma unroll
        for (int s = 0; s < BM / 64; ++s)
            gload_lds16(A + (size_t)(m0 + s * 64 + sr) * K + k0 + sc8,
                        As + s * 2048 + lds_elem);
#pragma unroll
        for (int s = 0; s < BN / 64; ++s)
            gload_lds16(B + (size_t)(n0 + s * 64 + sr) * K + k0 + sc8,
                        Bs + s * 2048 + lds_elem);
        __syncthreads();

        bf16x8 af[FI], bfr[FJ];
        const unsigned short* Ab = As + ((wr * (BM / 2) + (lane & 15)) * 32) + (lane >> 4) * 8;
        const unsigned short* Bb = Bs + ((wc * (BN / 2) + (lane & 15)) * 32) + (lane >> 4) * 8;
#pragma unroll
        for (int i = 0; i < FI; ++i) af[i]  = *(const bf16x8*)(Ab + i * 16 * 32);
#pragma unroll
        for (int j = 0; j < FJ; ++j) bfr[j] = *(const bf16x8*)(Bb + j * 16 * 32);
#pragma unroll
        for (int i = 0; i < FI; ++i)
#pragma unroll
            for (int j = 0; j < FJ; ++j)
                acc[i][j] = __builtin_amdgcn_mfma_f32_16x16x32_bf16(
                    af[i], bfr[j], acc[i][j], 0, 0, 0);
        __syncthreads();
    }

    // Epilogue. C/D: col = lane&15, row = (lane>>4)*4 + reg
    const int fr = lane >> 4;
    const int fc = lane & 15;
#pragma unroll
    for (int i = 0; i < FI; ++i) {
#pragma unroll
        for (int j = 0; j < FJ; ++j) {
            int n = n0 + wc * (BN / 2) + j * 16 + fc;
            int mbase = m0 + wr * (BM / 2) + i * 16 + fr * 4;
#pragma unroll
            for (int r = 0; r < 4; ++r) {
                int m = mbase + r;
                float val = acc[i][j][r];
                if constexpr (MODE == 0) {
                    val += e0[n];   // qkv bias, o = n in [0,1024)
                    if (n < 512) ob0[((size_t)z * NN + m) * NC + n] = f2bf(val * ATTN_SCALE);
                    else         ob1[((size_t)z * NN + m) * NC + (n - 512)] = f2bf(val);
                } else if constexpr (MODE == 1) {
                    val += e0[1024 + m];   // v bias, channel = m
                    ob0[((size_t)z * NC + m) * NN + n] = f2bf(val);
                } else if constexpr (MODE == 2) {
                    ob0[(size_t)z * bss + (size_t)m * NN + n] = f2bf(val);
                } else {   // MODE 4
                    size_t idx = ((size_t)z * NC + m) * NN + n;
                    outf[idx] = val + e0[m] + e1[idx];
                }
            }
        }
    }
}

// ---------------------------------------------------------------------------
// PV GEMM, double-buffered: O[p,c] = sum_m P[p,m] * V[m,c]
// A = SP (b,p,m) bf16 K-major; B = vt (b,c,m) bf16 K-major.
// BM=BN=128, BK=64 (two 32-wide panels per buffer), one barrier/iter.
// LDS 64 KB -> 2 blocks/CU (grid 512 caps at 2 anyway).
// ---------------------------------------------------------------------------
__global__ __launch_bounds__(256) void pv_gemm_db(
    const unsigned short* __restrict__ Abase,
    const unsigned short* __restrict__ Bbase,
    unsigned short* __restrict__ Ob)
{
    const int z = blockIdx.z;
    const size_t bss = (size_t)NN * NN, bnc = (size_t)NN * NC;
    const unsigned short* A = Abase + (size_t)z * bss;   // (p, m)
    const unsigned short* B = Bbase + (size_t)z * bnc;   // (c, m)
    const int m0 = blockIdx.y * 128;   // p-tile
    const int n0 = blockIdx.x * 128;   // c-tile

    // [buf][half][slab*2048 + wave region]
    __shared__ __attribute__((aligned(16))) unsigned short As[2][2][128 * 32];
    __shared__ __attribute__((aligned(16))) unsigned short Bs[2][2][128 * 32];

    const int t = threadIdx.x;
    const int lane = t & 63;
    const int w = t >> 6;
    const int wr = w >> 1, wc = w & 1;
    const int sr = w * 16 + (lane >> 2);
    const int sc8 = (lane & 3) * 8;
    const int lds_elem = w * 512;

    floatx4 acc[4][4] = {};

    auto stage = [&](int buf, int k0) {
#pragma unroll
        for (int h = 0; h < 2; ++h) {
            int kk = k0 + h * 32;
#pragma unroll
            for (int s = 0; s < 2; ++s) {
                gload_lds16(A + (size_t)(m0 + s * 64 + sr) * NN + kk + sc8,
                            &As[buf][h][s * 2048 + lds_elem]);
                gload_lds16(B + (size_t)(n0 + s * 64 + sr) * NN + kk + sc8,
                            &Bs[buf][h][s * 2048 + lds_elem]);
            }
        }
    };

    stage(0, 0);
    for (int kt = 0; kt < NN / 64; ++kt) {
        const int cur = kt & 1;
        __syncthreads();                       // staging of cur complete; prev reads done
        if (kt + 1 < NN / 64) stage(1 - cur, (kt + 1) * 64);   // prefetch next
#pragma unroll
        for (int h = 0; h < 2; ++h) {
            const unsigned short* Ab = &As[cur][h][((wr * 64 + (lane & 15)) * 32) + (lane >> 4) * 8];
            const unsigned short* Bb = &Bs[cur][h][((wc * 64 + (lane & 15)) * 32) + (lane >> 4) * 8];
            bf16x8 af[4], bfr[4];
#pragma unroll
            for (int i = 0; i < 4; ++i) af[i]  = *(const bf16x8*)(Ab + i * 16 * 32);
#pragma unroll
            for (int j = 0; j < 4; ++j) bfr[j] = *(const bf16x8*)(Bb + j * 16 * 32);
#pragma unroll
            for (int i = 0; i < 4; ++i)
#pragma unroll
                for (int j = 0; j < 4; ++j)
                    acc[i][j] = __builtin_amdgcn_mfma_f32_16x16x32_bf16(
                        af[i], bfr[j], acc[i][j], 0, 0, 0);
        }
    }

    const int fr = lane >> 4;
    const int fc = lane & 15;
#pragma unroll
    for (int i = 0; i < 4; ++i) {
#pragma unroll
        for (int j = 0; j < 4; ++j) {
            int n = n0 + wc * 64 + j * 16 + fc;
            int mbase = m0 + wr * 64 + i * 16 + fr * 4;
#pragma unroll
            for (int r = 0; r < 4; ++r) {
                int m = mbase + r;
                Ob[(size_t)z * bnc + (size_t)m * NC + n] = f2bf(acc[i][j][r]);
            }
        }
    }
}

// ---------------------------------------------------------------------------
// Softmax in-place on bf16 S rows: 16 contiguous elements per thread.
// grid = (row, batch)
// ---------------------------------------------------------------------------
__global__ __launch_bounds__(256) void softmax_kernel(unsigned short* __restrict__ SP)
{
    unsigned short* Pr = SP + ((size_t)blockIdx.y * NN + blockIdx.x) * NN;
    int t = threadIdx.x;
    union { uint4 q[2]; unsigned short s[16]; } u;
    u.q[0] = ((const uint4*)Pr)[t * 2];
    u.q[1] = ((const uint4*)Pr)[t * 2 + 1];
    float v[16];
    float m = -INFINITY;
#pragma unroll
    for (int i = 0; i < 16; ++i) {
        v[i] = bf2f(u.s[i]);
        m = fmaxf(m, v[i]);
    }
#pragma unroll
    for (int off = 32; off; off >>= 1) m = fmaxf(m, __shfl_xor(m, off, 64));
    __shared__ float red[4];
    int lane = t & 63, w = t >> 6;
    if (lane == 0) red[w] = m;
    __syncthreads();
    m = fmaxf(fmaxf(red[0], red[1]), fmaxf(red[2], red[3]));
    __syncthreads();
    float s = 0.f;
#pragma unroll
    for (int i = 0; i < 16; ++i) {
        v[i] = __expf(v[i] - m);
        s += v[i];
    }
#pragma unroll
    for (int off = 32; off; off >>= 1) s += __shfl_xor(s, off, 64);
    if (lane == 0) red[w] = s;
    __syncthreads();
    s = red[0] + red[1] + red[2] + red[3];
    float inv = 1.0f / s;
#pragma unroll
    for (int i = 0; i < 16; ++i) u.s[i] = f2bf(v[i] * inv);
    ((uint4*)Pr)[t * 2]     = u.q[0];
    ((uint4*)Pr)[t * 2 + 1] = u.q[1];
}

// ---------------------------------------------------------------------------
extern "C" void kernel_launch(void* const* d_in, const int* in_sizes, int n_in,
                              void* d_out, int out_size, void* d_ws, size_t ws_size,
                              hipStream_t stream)
{
    const float* x     = (const float*)d_in[0];
    const float* gn_w  = (const float*)d_in[1];
    const float* gn_b  = (const float*)d_in[2];
    const float* qkv_w = (const float*)d_in[3];
    const float* qkv_b = (const float*)d_in[4];
    const float* out_w = (const float*)d_in[5];
    const float* out_b = (const float*)d_in[6];
    float* out = (float*)d_out;

    const size_t bnc = (size_t)NN * NC;          // 2,097,152 per batch
    char* w = (char*)d_ws;
    float* ss   = (float*)w;                 w += 16384;
    float* part = (float*)w;                 w += 8192;
    unsigned short* wq = (unsigned short*)w; w += (size_t)1536 * 512 * 2;
    unsigned short* wo = (unsigned short*)w; w += (size_t)512 * 512 * 2;
    unsigned short* qt = (unsigned short*)w; w += NB * bnc * 2;   // (b,n,c) pre-scaled
    unsigned short* kt = (unsigned short*)w; w += NB * bnc * 2;   // (b,n,c)
    unsigned short* vt = (unsigned short*)w; w += NB * bnc * 2;   // (b,c,n)
    unsigned short* SP = (unsigned short*)w; w += (size_t)NB * NN * NN * 2; // 128 MB
    // Aliases (lifetime-disjoint):
    unsigned short* ht = SP;   // ht (b,n,c) dead before MODE 2 writes SP
    unsigned short* Ob = qt;   // Ob (b,n,c) written after qt last read (MODE 2)

    gn_partial_kernel<<<1024, 256, 0, stream>>>(x, part);
    gn_final_kernel<<<1, 128, 0, stream>>>(part, gn_w, gn_b, ss);
    wconv_kernel<<<(1536 * 512 + 512 * 512) / 256, 256, 0, stream>>>(qkv_w, out_w, wq, wo);
    htnorm_kernel<<<dim3(NN / 32, NC / 32, NB), 256, 0, stream>>>(x, ss, ht);

    // q/k: C[p,o] = ht · wqk^T   (q pre-scaled by ATTN_SCALE)
    mfma_gemm<0, 128, 128><<<dim3(1024 / 128, NN / 128, NB), 256, 0, stream>>>(
        ht, wq, qkv_b, nullptr, nullptr, qt, kt);
    // v: C[c,p] = wv · ht^T
    mfma_gemm<1, 128, 128><<<dim3(NN / 128, 512 / 128, NB), 256, 0, stream>>>(
        wq + (size_t)1024 * 512, ht, qkv_b, nullptr, nullptr, vt, nullptr);

    // QK^T, all batches, one dispatch
    mfma_gemm<2, 128, 128><<<dim3(NN / 128, NN / 128, NB), 256, 0, stream>>>(
        qt, kt, nullptr, nullptr, nullptr, SP, nullptr);
    // softmax, all batches
    softmax_kernel<<<dim3(NN, NB), 256, 0, stream>>>(SP);
    // PV, all batches, double-buffered BK=64
    pv_gemm_db<<<dim3(512 / 128, NN / 128, NB), 256, 0, stream>>>(SP, vt, Ob);

    // out projection + bias + residual
    mfma_gemm<4, 128, 128><<<dim3(NN / 128, 512 / 128, NB), 256, 0, stream>>>(
        wo, Ob, out_b, x, out, nullptr, nullptr);
}

// Round 6
// 408.854 us; speedup vs baseline: 7.2774x; 1.0263x over previous
//
#include <hip/hip_runtime.h>
#include <cmath>

// b=4, c=512, h=w=64 -> n=4096, groups=32 (16 ch/group)
#define NB 4
#define NC 512
#define NN 4096
#define ATTN_SCALE 0.04419417382415922f  // 512^-0.5

typedef __bf16 bf16x8 __attribute__((ext_vector_type(8)));
typedef float floatx4 __attribute__((ext_vector_type(4)));

__device__ __forceinline__ unsigned short f2bf(float f) {
    union { float f; unsigned int u; } v; v.f = f;
    return (unsigned short)((v.u + 0x7fffu + ((v.u >> 16) & 1u)) >> 16);
}
__device__ __forceinline__ float bf2f(unsigned short u) {
    union { unsigned int u; float f; } v; v.u = ((unsigned int)u) << 16;
    return v.f;
}

__device__ __forceinline__ void gload_lds16(const unsigned short* gp, unsigned short* lp) {
    __builtin_amdgcn_global_load_lds(
        (const __attribute__((address_space(1))) void*)gp,
        (__attribute__((address_space(3))) void*)lp, 16, 0, 0);
}

// ---------------------------------------------------------------------------
// Kernel 1a: GroupNorm partial sums. 1024 blocks = (b,g) x 8 slices.
// ---------------------------------------------------------------------------
__global__ __launch_bounds__(256) void gn_partial_kernel(
    const float* __restrict__ x, float* __restrict__ part)
{
    int blk = blockIdx.x;
    int bg = blk >> 3, sub = blk & 7;
    const float4* xv = (const float4*)(x + (size_t)bg * 16 * NN + (size_t)sub * 8192);
    float s1 = 0.f, s2 = 0.f;
#pragma unroll
    for (int i = 0; i < 8; ++i) {
        float4 v = xv[threadIdx.x + i * 256];
        s1 += v.x + v.y + v.z + v.w;
        s2 += v.x * v.x + v.y * v.y + v.z * v.z + v.w * v.w;
    }
#pragma unroll
    for (int off = 32; off; off >>= 1) {
        s1 += __shfl_xor(s1, off, 64);
        s2 += __shfl_xor(s2, off, 64);
    }
    __shared__ float r1[4], r2[4];
    int lane = threadIdx.x & 63, w = threadIdx.x >> 6;
    if (lane == 0) { r1[w] = s1; r2[w] = s2; }
    __syncthreads();
    if (threadIdx.x == 0) {
        part[blk * 2]     = r1[0] + r1[1] + r1[2] + r1[3];
        part[blk * 2 + 1] = r2[0] + r2[1] + r2[2] + r2[3];
    }
}

// Kernel 1b: finalize -> per-channel scale/shift
__global__ __launch_bounds__(128) void gn_final_kernel(
    const float* __restrict__ part, const float* __restrict__ gw,
    const float* __restrict__ gb, float* __restrict__ ss)
{
    int tg = threadIdx.x;            // 0..127 = b*32+g
    int b = tg >> 5, g = tg & 31;
    float s1 = 0.f, s2 = 0.f;
#pragma unroll
    for (int s = 0; s < 8; ++s) {
        s1 += part[(tg * 8 + s) * 2];
        s2 += part[(tg * 8 + s) * 2 + 1];
    }
    float mean = s1 * (1.0f / 65536.0f);
    float var  = s2 * (1.0f / 65536.0f) - mean * mean;
    float rstd = rsqrtf(var + 1e-5f);
#pragma unroll
    for (int i = 0; i < 16; ++i) {
        int c = g * 16 + i;
        float sc = rstd * gw[c];
        ss[b * NC + c] = sc;
        ss[2048 + b * NC + c] = gb[c] - mean * sc;
    }
}

// ---------------------------------------------------------------------------
// Kernel 2: convert weights fp32 -> bf16
// ---------------------------------------------------------------------------
__global__ __launch_bounds__(256) void wconv_kernel(
    const float* __restrict__ qkv_w, const float* __restrict__ out_w,
    unsigned short* __restrict__ wq, unsigned short* __restrict__ wo)
{
    int i = blockIdx.x * 256 + threadIdx.x;
    const int NQ = 1536 * 512;
    if (i < NQ) wq[i] = f2bf(qkv_w[i]);
    else        wo[i - NQ] = f2bf(out_w[i - NQ]);
}

// ---------------------------------------------------------------------------
// Kernel 3: normalize + transpose: x (b,c,n) fp32 -> h_t (b,n,c) bf16
// ---------------------------------------------------------------------------
__global__ __launch_bounds__(256) void htnorm_kernel(
    const float* __restrict__ x, const float* __restrict__ ss,
    unsigned short* __restrict__ ht)
{
    int b = blockIdx.z;
    int c0 = blockIdx.y * 32, n0 = blockIdx.x * 32;
    __shared__ float T[32][33];
    int tx = threadIdx.x & 31, ty = threadIdx.x >> 5;   // ty 0..7
    const float* xb = x + ((size_t)b * NC + c0) * NN;
    const float* sc = ss + b * NC + c0;
    const float* sh = ss + 2048 + b * NC + c0;
#pragma unroll
    for (int i = 0; i < 4; ++i) {
        int c = ty + i * 8;
        T[c][tx] = xb[(size_t)c * NN + n0 + tx] * sc[c] + sh[c];
    }
    __syncthreads();
    unsigned short* hb = ht + ((size_t)b * NN + n0) * NC + c0;
#pragma unroll
    for (int i = 0; i < 4; ++i) {
        int n = ty + i * 8;
        hb[(size_t)n * NC + tx] = f2bf(T[tx][n]);
    }
}

// ---------------------------------------------------------------------------
// MFMA NT GEMM: C[m,n] = sum_k A[m,k]*B[n,k], BMxBN block tile, BK=32.
// MODE 0: qkv q/k   M=4096 N=1024 K=512  A=ht(+z) B=wqk    -> qt(*scale)/kt +bias
// MODE 1: qkv v     M=512  N=4096 K=512  A=wv     B=ht(+z) -> vt (c,p) bf16 +bias
// MODE 2: QK^T      M=4096 N=4096 K=512  A=qt(+z) B=kt(+z) -> SP = exp(s) bf16,
//                   row-sums atomically accumulated into outf = L[b*NN+row]
// MODE 4: out proj  M=512  N=4096 K=512  A=wo     B=Ob(+z) -> out fp32 +bias+res
// ---------------------------------------------------------------------------
template<int MODE, int BM, int BN>
__global__ __launch_bounds__(256) void mfma_gemm(
    const unsigned short* __restrict__ Abase,
    const unsigned short* __restrict__ Bbase,
    const float* __restrict__ e0, const float* __restrict__ e1,
    float* __restrict__ outf,
    unsigned short* __restrict__ ob0, unsigned short* __restrict__ ob1)
{
    constexpr int K = 512;
    constexpr int FI = BM / 32;       // frag rows per wave
    constexpr int FJ = BN / 32;       // frag cols per wave
    const int z = blockIdx.z;
    const size_t bnc = (size_t)NN * NC;
    const size_t bss = (size_t)NN * NN;

    const unsigned short* A;
    const unsigned short* B;
    if constexpr (MODE == 0)      { A = Abase + (size_t)z * bnc; B = Bbase; }
    else if constexpr (MODE == 1) { A = Abase; B = Bbase + (size_t)z * bnc; }
    else if constexpr (MODE == 2) { A = Abase + (size_t)z * bnc; B = Bbase + (size_t)z * bnc; }
    else                          { A = Abase; B = Bbase + (size_t)z * bnc; }

    const int m0 = blockIdx.y * BM;
    const int n0 = blockIdx.x * BN;

    __shared__ __attribute__((aligned(16))) unsigned short As[BM * 32];
    __shared__ __attribute__((aligned(16))) unsigned short Bs[BN * 32];

    const int t = threadIdx.x;
    const int lane = t & 63;
    const int w = t >> 6;
    const int wr = w >> 1, wc = w & 1;

    const int sr = w * 16 + (lane >> 2);       // staging row within 64-row slab
    const int sc8 = (lane & 3) * 8;            // element offset within 32
    const int lds_elem = w * 512;

    floatx4 acc[FI][FJ] = {};

    for (int k0 = 0; k0 < K; k0 += 32) {
#pragma unroll
        for (int s = 0; s < BM / 64; ++s)
            gload_lds16(A + (size_t)(m0 + s * 64 + sr) * K + k0 + sc8,
                        As + s * 2048 + lds_elem);
#pragma unroll
        for (int s = 0; s < BN / 64; ++s)
            gload_lds16(B + (size_t)(n0 + s * 64 + sr) * K + k0 + sc8,
                        Bs + s * 2048 + lds_elem);
        __syncthreads();

        bf16x8 af[FI], bfr[FJ];
        const unsigned short* Ab = As + ((wr * (BM / 2) + (lane & 15)) * 32) + (lane >> 4) * 8;
        const unsigned short* Bb = Bs + ((wc * (BN / 2) + (lane & 15)) * 32) + (lane >> 4) * 8;
#pragma unroll
        for (int i = 0; i < FI; ++i) af[i]  = *(const bf16x8*)(Ab + i * 16 * 32);
#pragma unroll
        for (int j = 0; j < FJ; ++j) bfr[j] = *(const bf16x8*)(Bb + j * 16 * 32);
#pragma unroll
        for (int i = 0; i < FI; ++i)
#pragma unroll
            for (int j = 0; j < FJ; ++j)
                acc[i][j] = __builtin_amdgcn_mfma_f32_16x16x32_bf16(
                    af[i], bfr[j], acc[i][j], 0, 0, 0);
        __syncthreads();
    }

    // Epilogue. C/D: col = lane&15, row = (lane>>4)*4 + reg
    const int fr = lane >> 4;
    const int fc = lane & 15;

    if constexpr (MODE == 2) {
        // exp + store bf16 + per-row sum (16-lane reduce + atomicAdd to L)
        float rs[FI][4];
#pragma unroll
        for (int i = 0; i < FI; ++i)
#pragma unroll
            for (int r = 0; r < 4; ++r) rs[i][r] = 0.f;
#pragma unroll
        for (int i = 0; i < FI; ++i) {
#pragma unroll
            for (int j = 0; j < FJ; ++j) {
                int n = n0 + wc * (BN / 2) + j * 16 + fc;
                int mbase = m0 + wr * (BM / 2) + i * 16 + fr * 4;
#pragma unroll
                for (int r = 0; r < 4; ++r) {
                    float e = __expf(acc[i][j][r]);
                    unsigned short us = f2bf(e);
                    ob0[(size_t)z * bss + (size_t)(mbase + r) * NN + n] = us;
                    rs[i][r] += bf2f(us);   // sum the rounded values for consistency
                }
            }
        }
        // reduce over the 16 lanes of each quad (same rows, fc=0..15)
#pragma unroll
        for (int i = 0; i < FI; ++i) {
#pragma unroll
            for (int r = 0; r < 4; ++r) {
                float v = rs[i][r];
                v += __shfl_xor(v, 1, 16);
                v += __shfl_xor(v, 2, 16);
                v += __shfl_xor(v, 4, 16);
                v += __shfl_xor(v, 8, 16);
                if (fc == 0) {
                    int m = m0 + wr * (BM / 2) + i * 16 + fr * 4 + r;
                    atomicAdd(&outf[z * NN + m], v);
                }
            }
        }
        return;
    }

#pragma unroll
    for (int i = 0; i < FI; ++i) {
#pragma unroll
        for (int j = 0; j < FJ; ++j) {
            int n = n0 + wc * (BN / 2) + j * 16 + fc;
            int mbase = m0 + wr * (BM / 2) + i * 16 + fr * 4;
#pragma unroll
            for (int r = 0; r < 4; ++r) {
                int m = mbase + r;
                float val = acc[i][j][r];
                if constexpr (MODE == 0) {
                    val += e0[n];   // qkv bias, o = n in [0,1024)
                    if (n < 512) ob0[((size_t)z * NN + m) * NC + n] = f2bf(val * ATTN_SCALE);
                    else         ob1[((size_t)z * NN + m) * NC + (n - 512)] = f2bf(val);
                } else if constexpr (MODE == 1) {
                    val += e0[1024 + m];   // v bias, channel = m
                    ob0[((size_t)z * NC + m) * NN + n] = f2bf(val);
                } else {   // MODE 4
                    size_t idx = ((size_t)z * NC + m) * NN + n;
                    outf[idx] = val + e0[m] + e1[idx];
                }
            }
        }
    }
}

// ---------------------------------------------------------------------------
// PV GEMM, double-buffered: O[p,c] = (sum_m P[p,m] * V[m,c]) / L[p]
// A = SP (b,p,m) bf16 (unnormalized exp), B = vt (b,c,m) bf16.
// BM=BN=128, BK=64, one barrier/iter.
// ---------------------------------------------------------------------------
__global__ __launch_bounds__(256) void pv_gemm_db(
    const unsigned short* __restrict__ Abase,
    const unsigned short* __restrict__ Bbase,
    const float* __restrict__ L,
    unsigned short* __restrict__ Ob)
{
    const int z = blockIdx.z;
    const size_t bss = (size_t)NN * NN, bnc = (size_t)NN * NC;
    const unsigned short* A = Abase + (size_t)z * bss;   // (p, m)
    const unsigned short* B = Bbase + (size_t)z * bnc;   // (c, m)
    const int m0 = blockIdx.y * 128;   // p-tile
    const int n0 = blockIdx.x * 128;   // c-tile

    __shared__ __attribute__((aligned(16))) unsigned short As[2][2][128 * 32];
    __shared__ __attribute__((aligned(16))) unsigned short Bs[2][2][128 * 32];

    const int t = threadIdx.x;
    const int lane = t & 63;
    const int w = t >> 6;
    const int wr = w >> 1, wc = w & 1;
    const int sr = w * 16 + (lane >> 2);
    const int sc8 = (lane & 3) * 8;
    const int lds_elem = w * 512;

    floatx4 acc[4][4] = {};

    auto stage = [&](int buf, int k0) {
#pragma unroll
        for (int h = 0; h < 2; ++h) {
            int kk = k0 + h * 32;
#pragma unroll
            for (int s = 0; s < 2; ++s) {
                gload_lds16(A + (size_t)(m0 + s * 64 + sr) * NN + kk + sc8,
                            &As[buf][h][s * 2048 + lds_elem]);
                gload_lds16(B + (size_t)(n0 + s * 64 + sr) * NN + kk + sc8,
                            &Bs[buf][h][s * 2048 + lds_elem]);
            }
        }
    };

    stage(0, 0);
    for (int kt = 0; kt < NN / 64; ++kt) {
        const int cur = kt & 1;
        __syncthreads();
        if (kt + 1 < NN / 64) stage(1 - cur, (kt + 1) * 64);
#pragma unroll
        for (int h = 0; h < 2; ++h) {
            const unsigned short* Ab = &As[cur][h][((wr * 64 + (lane & 15)) * 32) + (lane >> 4) * 8];
            const unsigned short* Bb = &Bs[cur][h][((wc * 64 + (lane & 15)) * 32) + (lane >> 4) * 8];
            bf16x8 af[4], bfr[4];
#pragma unroll
            for (int i = 0; i < 4; ++i) af[i]  = *(const bf16x8*)(Ab + i * 16 * 32);
#pragma unroll
            for (int j = 0; j < 4; ++j) bfr[j] = *(const bf16x8*)(Bb + j * 16 * 32);
#pragma unroll
            for (int i = 0; i < 4; ++i)
#pragma unroll
                for (int j = 0; j < 4; ++j)
                    acc[i][j] = __builtin_amdgcn_mfma_f32_16x16x32_bf16(
                        af[i], bfr[j], acc[i][j], 0, 0, 0);
        }
    }

    const int fr = lane >> 4;
    const int fc = lane & 15;
#pragma unroll
    for (int i = 0; i < 4; ++i) {
#pragma unroll
        for (int r = 0; r < 4; ++r) {
            int m = m0 + wr * 64 + i * 16 + fr * 4 + r;
            float linv = 1.0f / L[z * NN + m];
#pragma unroll
            for (int j = 0; j < 4; ++j) {
                int n = n0 + wc * 64 + j * 16 + fc;
                Ob[(size_t)z * bnc + (size_t)m * NC + n] = f2bf(acc[i][j][r] * linv);
            }
        }
    }
}

// ---------------------------------------------------------------------------
extern "C" void kernel_launch(void* const* d_in, const int* in_sizes, int n_in,
                              void* d_out, int out_size, void* d_ws, size_t ws_size,
                              hipStream_t stream)
{
    const float* x     = (const float*)d_in[0];
    const float* gn_w  = (const float*)d_in[1];
    const float* gn_b  = (const float*)d_in[2];
    const float* qkv_w = (const float*)d_in[3];
    const float* qkv_b = (const float*)d_in[4];
    const float* out_w = (const float*)d_in[5];
    const float* out_b = (const float*)d_in[6];
    float* out = (float*)d_out;

    const size_t bnc = (size_t)NN * NC;          // 2,097,152 per batch
    char* w = (char*)d_ws;
    float* ss   = (float*)w;                 w += 16384;
    float* part = (float*)w;                 w += 8192;
    float* Lsum = (float*)w;                 w += (size_t)NB * NN * 4;  // row sums
    unsigned short* wq = (unsigned short*)w; w += (size_t)1536 * 512 * 2;
    unsigned short* wo = (unsigned short*)w; w += (size_t)512 * 512 * 2;
    unsigned short* qt = (unsigned short*)w; w += NB * bnc * 2;   // (b,n,c) pre-scaled
    unsigned short* kt = (unsigned short*)w; w += NB * bnc * 2;   // (b,n,c)
    unsigned short* vt = (unsigned short*)w; w += NB * bnc * 2;   // (b,c,n)
    unsigned short* SP = (unsigned short*)w; w += (size_t)NB * NN * NN * 2; // 128 MB
    // Aliases (lifetime-disjoint):
    unsigned short* ht = SP;   // ht (b,n,c) dead before MODE 2 writes SP
    unsigned short* Ob = qt;   // Ob (b,n,c) written after qt last read (MODE 2)

    hipMemsetAsync(Lsum, 0, (size_t)NB * NN * sizeof(float), stream);

    gn_partial_kernel<<<1024, 256, 0, stream>>>(x, part);
    gn_final_kernel<<<1, 128, 0, stream>>>(part, gn_w, gn_b, ss);
    wconv_kernel<<<(1536 * 512 + 512 * 512) / 256, 256, 0, stream>>>(qkv_w, out_w, wq, wo);
    htnorm_kernel<<<dim3(NN / 32, NC / 32, NB), 256, 0, stream>>>(x, ss, ht);

    // q/k: C[p,o] = ht · wqk^T   (q pre-scaled by ATTN_SCALE)
    mfma_gemm<0, 128, 128><<<dim3(1024 / 128, NN / 128, NB), 256, 0, stream>>>(
        ht, wq, qkv_b, nullptr, nullptr, qt, kt);
    // v: C[c,p] = wv · ht^T
    mfma_gemm<1, 128, 128><<<dim3(NN / 128, 512 / 128, NB), 256, 0, stream>>>(
        wq + (size_t)1024 * 512, ht, qkv_b, nullptr, nullptr, vt, nullptr);

    // QK^T + exp + row-sum accumulation, all batches, one dispatch
    mfma_gemm<2, 128, 128><<<dim3(NN / 128, NN / 128, NB), 256, 0, stream>>>(
        qt, kt, nullptr, nullptr, Lsum, SP, nullptr);
    // PV + normalize, all batches
    pv_gemm_db<<<dim3(512 / 128, NN / 128, NB), 256, 0, stream>>>(SP, vt, Lsum, Ob);

    // out projection + bias + residual
    mfma_gemm<4, 128, 128><<<dim3(NN / 128, 512 / 128, NB), 256, 0, stream>>>(
        wo, Ob, out_b, x, out, nullptr, nullptr);
}

// Round 7
// 408.755 us; speedup vs baseline: 7.2792x; 1.0002x over previous
//
#include <hip/hip_runtime.h>
#include <cmath>

// b=4, c=512, h=w=64 -> n=4096, groups=32 (16 ch/group)
#define NB 4
#define NC 512
#define NN 4096
#define ATTN_SCALE 0.04419417382415922f  // 512^-0.5

typedef __bf16 bf16x8 __attribute__((ext_vector_type(8)));
typedef float floatx4 __attribute__((ext_vector_type(4)));

__device__ __forceinline__ unsigned short f2bf(float f) {
    union { float f; unsigned int u; } v; v.f = f;
    return (unsigned short)((v.u + 0x7fffu + ((v.u >> 16) & 1u)) >> 16);
}
__device__ __forceinline__ unsigned short f2bf_trunc(float f) {
    union { float f; unsigned int u; } v; v.f = f;
    return (unsigned short)(v.u >> 16);
}
__device__ __forceinline__ float bf2f(unsigned short u) {
    union { unsigned int u; float f; } v; v.u = ((unsigned int)u) << 16;
    return v.f;
}

__device__ __forceinline__ void gload_lds16(const unsigned short* gp, unsigned short* lp) {
    __builtin_amdgcn_global_load_lds(
        (const __attribute__((address_space(1))) void*)gp,
        (__attribute__((address_space(3))) void*)lp, 16, 0, 0);
}

// ---------------------------------------------------------------------------
// Kernel 1a: GroupNorm partial sums. 1024 blocks = (b,g) x 8 slices.
// ---------------------------------------------------------------------------
__global__ __launch_bounds__(256) void gn_partial_kernel(
    const float* __restrict__ x, float* __restrict__ part)
{
    int blk = blockIdx.x;
    int bg = blk >> 3, sub = blk & 7;
    const float4* xv = (const float4*)(x + (size_t)bg * 16 * NN + (size_t)sub * 8192);
    float s1 = 0.f, s2 = 0.f;
#pragma unroll
    for (int i = 0; i < 8; ++i) {
        float4 v = xv[threadIdx.x + i * 256];
        s1 += v.x + v.y + v.z + v.w;
        s2 += v.x * v.x + v.y * v.y + v.z * v.z + v.w * v.w;
    }
#pragma unroll
    for (int off = 32; off; off >>= 1) {
        s1 += __shfl_xor(s1, off, 64);
        s2 += __shfl_xor(s2, off, 64);
    }
    __shared__ float r1[4], r2[4];
    int lane = threadIdx.x & 63, w = threadIdx.x >> 6;
    if (lane == 0) { r1[w] = s1; r2[w] = s2; }
    __syncthreads();
    if (threadIdx.x == 0) {
        part[blk * 2]     = r1[0] + r1[1] + r1[2] + r1[3];
        part[blk * 2 + 1] = r2[0] + r2[1] + r2[2] + r2[3];
    }
}

// Kernel 1b: finalize -> per-channel scale/shift
__global__ __launch_bounds__(128) void gn_final_kernel(
    const float* __restrict__ part, const float* __restrict__ gw,
    const float* __restrict__ gb, float* __restrict__ ss)
{
    int tg = threadIdx.x;            // 0..127 = b*32+g
    int b = tg >> 5, g = tg & 31;
    float s1 = 0.f, s2 = 0.f;
#pragma unroll
    for (int s = 0; s < 8; ++s) {
        s1 += part[(tg * 8 + s) * 2];
        s2 += part[(tg * 8 + s) * 2 + 1];
    }
    float mean = s1 * (1.0f / 65536.0f);
    float var  = s2 * (1.0f / 65536.0f) - mean * mean;
    float rstd = rsqrtf(var + 1e-5f);
#pragma unroll
    for (int i = 0; i < 16; ++i) {
        int c = g * 16 + i;
        float sc = rstd * gw[c];
        ss[b * NC + c] = sc;
        ss[2048 + b * NC + c] = gb[c] - mean * sc;
    }
}

// ---------------------------------------------------------------------------
// Kernel 2: convert weights fp32 -> bf16
// ---------------------------------------------------------------------------
__global__ __launch_bounds__(256) void wconv_kernel(
    const float* __restrict__ qkv_w, const float* __restrict__ out_w,
    unsigned short* __restrict__ wq, unsigned short* __restrict__ wo)
{
    int i = blockIdx.x * 256 + threadIdx.x;
    const int NQ = 1536 * 512;
    if (i < NQ) wq[i] = f2bf(qkv_w[i]);
    else        wo[i - NQ] = f2bf(out_w[i - NQ]);
}

// ---------------------------------------------------------------------------
// Kernel 3: normalize + transpose: x (b,c,n) fp32 -> h_t (b,n,c) bf16
// ---------------------------------------------------------------------------
__global__ __launch_bounds__(256) void htnorm_kernel(
    const float* __restrict__ x, const float* __restrict__ ss,
    unsigned short* __restrict__ ht)
{
    int b = blockIdx.z;
    int c0 = blockIdx.y * 32, n0 = blockIdx.x * 32;
    __shared__ float T[32][33];
    int tx = threadIdx.x & 31, ty = threadIdx.x >> 5;   // ty 0..7
    const float* xb = x + ((size_t)b * NC + c0) * NN;
    const float* sc = ss + b * NC + c0;
    const float* sh = ss + 2048 + b * NC + c0;
#pragma unroll
    for (int i = 0; i < 4; ++i) {
        int c = ty + i * 8;
        T[c][tx] = xb[(size_t)c * NN + n0 + tx] * sc[c] + sh[c];
    }
    __syncthreads();
    unsigned short* hb = ht + ((size_t)b * NN + n0) * NC + c0;
#pragma unroll
    for (int i = 0; i < 4; ++i) {
        int n = ty + i * 8;
        hb[(size_t)n * NC + tx] = f2bf(T[tx][n]);
    }
}

// ---------------------------------------------------------------------------
// MFMA NT GEMM: C[m,n] = sum_k A[m,k]*B[n,k], BMxBN block tile, BK=32.
// MODE 0: qkv q/k   M=4096 N=1024 K=512  A=ht(+z) B=wqk    -> qt(*scale)/kt +bias
// MODE 1: qkv v     M=512  N=4096 K=512  A=wv     B=ht(+z) -> vt (c,p) bf16 +bias
// MODE 2: QK^T      M=4096 N=4096 K=512  A=qt(+z) B=kt(+z) -> SP = exp(s) bf16,
//                   row-sums atomically accumulated into outf = L[b*NN+row]
// MODE 4: out proj  M=512  N=4096 K=512  A=wo     B=Ob(+z) -> out fp32 +bias+res
// ---------------------------------------------------------------------------
template<int MODE, int BM, int BN>
__global__ __launch_bounds__(256, 3) void mfma_gemm(
    const unsigned short* __restrict__ Abase,
    const unsigned short* __restrict__ Bbase,
    const float* __restrict__ e0, const float* __restrict__ e1,
    float* __restrict__ outf,
    unsigned short* __restrict__ ob0, unsigned short* __restrict__ ob1)
{
    constexpr int K = 512;
    constexpr int FI = BM / 32;       // frag rows per wave
    constexpr int FJ = BN / 32;       // frag cols per wave
    const int z = blockIdx.z;
    const size_t bnc = (size_t)NN * NC;
    const size_t bss = (size_t)NN * NN;

    const unsigned short* A;
    const unsigned short* B;
    if constexpr (MODE == 0)      { A = Abase + (size_t)z * bnc; B = Bbase; }
    else if constexpr (MODE == 1) { A = Abase; B = Bbase + (size_t)z * bnc; }
    else if constexpr (MODE == 2) { A = Abase + (size_t)z * bnc; B = Bbase + (size_t)z * bnc; }
    else                          { A = Abase; B = Bbase + (size_t)z * bnc; }

    const int m0 = blockIdx.y * BM;
    const int n0 = blockIdx.x * BN;

    __shared__ __attribute__((aligned(16))) unsigned short As[BM * 32];
    __shared__ __attribute__((aligned(16))) unsigned short Bs[BN * 32];

    const int t = threadIdx.x;
    const int lane = t & 63;
    const int w = t >> 6;
    const int wr = w >> 1, wc = w & 1;

    const int sr = w * 16 + (lane >> 2);       // staging row within 64-row slab
    const int sc8 = (lane & 3) * 8;            // element offset within 32
    const int lds_elem = w * 512;

    floatx4 acc[FI][FJ] = {};

    for (int k0 = 0; k0 < K; k0 += 32) {
#pragma unroll
        for (int s = 0; s < BM / 64; ++s)
            gload_lds16(A + (size_t)(m0 + s * 64 + sr) * K + k0 + sc8,
                        As + s * 2048 + lds_elem);
#pragma unroll
        for (int s = 0; s < BN / 64; ++s)
            gload_lds16(B + (size_t)(n0 + s * 64 + sr) * K + k0 + sc8,
                        Bs + s * 2048 + lds_elem);
        __syncthreads();

        bf16x8 af[FI], bfr[FJ];
        const unsigned short* Ab = As + ((wr * (BM / 2) + (lane & 15)) * 32) + (lane >> 4) * 8;
        const unsigned short* Bb = Bs + ((wc * (BN / 2) + (lane & 15)) * 32) + (lane >> 4) * 8;
#pragma unroll
        for (int i = 0; i < FI; ++i) af[i]  = *(const bf16x8*)(Ab + i * 16 * 32);
#pragma unroll
        for (int j = 0; j < FJ; ++j) bfr[j] = *(const bf16x8*)(Bb + j * 16 * 32);
#pragma unroll
        for (int i = 0; i < FI; ++i)
#pragma unroll
            for (int j = 0; j < FJ; ++j)
                acc[i][j] = __builtin_amdgcn_mfma_f32_16x16x32_bf16(
                    af[i], bfr[j], acc[i][j], 0, 0, 0);
        __syncthreads();
    }

    // Epilogue. C/D: col = lane&15, row = (lane>>4)*4 + reg
    const int fr = lane >> 4;
    const int fc = lane & 15;

    if constexpr (MODE == 2) {
        // exp + truncated bf16 store + per-row sum (16-lane reduce + atomicAdd)
        float rs[FI][4];
#pragma unroll
        for (int i = 0; i < FI; ++i)
#pragma unroll
            for (int r = 0; r < 4; ++r) rs[i][r] = 0.f;
#pragma unroll
        for (int i = 0; i < FI; ++i) {
#pragma unroll
            for (int j = 0; j < FJ; ++j) {
                int n = n0 + wc * (BN / 2) + j * 16 + fc;
                int mbase = m0 + wr * (BM / 2) + i * 16 + fr * 4;
#pragma unroll
                for (int r = 0; r < 4; ++r) {
                    float e = __expf(acc[i][j][r]);
                    ob0[(size_t)z * bss + (size_t)(mbase + r) * NN + n] = f2bf_trunc(e);
                    rs[i][r] += e;
                }
            }
        }
#pragma unroll
        for (int i = 0; i < FI; ++i) {
#pragma unroll
            for (int r = 0; r < 4; ++r) {
                float v = rs[i][r];
                v += __shfl_xor(v, 1, 16);
                v += __shfl_xor(v, 2, 16);
                v += __shfl_xor(v, 4, 16);
                v += __shfl_xor(v, 8, 16);
                if (fc == 0) {
                    int m = m0 + wr * (BM / 2) + i * 16 + fr * 4 + r;
                    atomicAdd(&outf[z * NN + m], v);
                }
            }
        }
        return;
    }

#pragma unroll
    for (int i = 0; i < FI; ++i) {
#pragma unroll
        for (int j = 0; j < FJ; ++j) {
            int n = n0 + wc * (BN / 2) + j * 16 + fc;
            int mbase = m0 + wr * (BM / 2) + i * 16 + fr * 4;
#pragma unroll
            for (int r = 0; r < 4; ++r) {
                int m = mbase + r;
                float val = acc[i][j][r];
                if constexpr (MODE == 0) {
                    val += e0[n];   // qkv bias, o = n in [0,1024)
                    if (n < 512) ob0[((size_t)z * NN + m) * NC + n] = f2bf(val * ATTN_SCALE);
                    else         ob1[((size_t)z * NN + m) * NC + (n - 512)] = f2bf(val);
                } else if constexpr (MODE == 1) {
                    val += e0[1024 + m];   // v bias, channel = m
                    ob0[((size_t)z * NC + m) * NN + n] = f2bf(val);
                } else {   // MODE 4
                    size_t idx = ((size_t)z * NC + m) * NN + n;
                    outf[idx] = val + e0[m] + e1[idx];
                }
            }
        }
    }
}

// ---------------------------------------------------------------------------
// PV GEMM: O[p,c] = (sum_m P[p,m] * V[m,c]) / L[p]
// BM=64 (p), BN=256 (c), BK=32, single-buffered.
// SP re-read factor 2 (vs 4 at BN=128); LDS 20KB; launch_bounds(256,3) -> 3 blk/CU.
// ---------------------------------------------------------------------------
__global__ __launch_bounds__(256, 3) void pv_gemm(
    const unsigned short* __restrict__ Abase,
    const unsigned short* __restrict__ Bbase,
    const float* __restrict__ L,
    unsigned short* __restrict__ Ob)
{
    const int z = blockIdx.z;
    const size_t bss = (size_t)NN * NN, bnc = (size_t)NN * NC;
    const unsigned short* A = Abase + (size_t)z * bss;   // (p, m)
    const unsigned short* B = Bbase + (size_t)z * bnc;   // (c, m)
    const int m0 = blockIdx.y * 64;    // p-tile
    const int n0 = blockIdx.x * 256;   // c-tile

    __shared__ __attribute__((aligned(16))) unsigned short As[64 * 32];    // 4 KB
    __shared__ __attribute__((aligned(16))) unsigned short Bs[256 * 32];   // 16 KB

    const int t = threadIdx.x;
    const int lane = t & 63;
    const int w = t >> 6;
    const int wr = w >> 1, wc = w & 1;
    const int sr = w * 16 + (lane >> 2);
    const int sc8 = (lane & 3) * 8;
    const int lds_elem = w * 512;

    floatx4 acc[2][8] = {};

    for (int k0 = 0; k0 < NN; k0 += 32) {
        gload_lds16(A + (size_t)(m0 + sr) * NN + k0 + sc8, As + lds_elem);
#pragma unroll
        for (int s = 0; s < 4; ++s)
            gload_lds16(B + (size_t)(n0 + s * 64 + sr) * NN + k0 + sc8,
                        Bs + s * 2048 + lds_elem);
        __syncthreads();

        bf16x8 af[2], bfr[8];
        const unsigned short* Ab = As + ((wr * 32 + (lane & 15)) * 32) + (lane >> 4) * 8;
        const unsigned short* Bb = Bs + ((wc * 128 + (lane & 15)) * 32) + (lane >> 4) * 8;
#pragma unroll
        for (int i = 0; i < 2; ++i) af[i]  = *(const bf16x8*)(Ab + i * 16 * 32);
#pragma unroll
        for (int j = 0; j < 8; ++j) bfr[j] = *(const bf16x8*)(Bb + j * 16 * 32);
#pragma unroll
        for (int i = 0; i < 2; ++i)
#pragma unroll
            for (int j = 0; j < 8; ++j)
                acc[i][j] = __builtin_amdgcn_mfma_f32_16x16x32_bf16(
                    af[i], bfr[j], acc[i][j], 0, 0, 0);
        __syncthreads();
    }

    const int fr = lane >> 4;
    const int fc = lane & 15;
#pragma unroll
    for (int i = 0; i < 2; ++i) {
#pragma unroll
        for (int r = 0; r < 4; ++r) {
            int m = m0 + wr * 32 + i * 16 + fr * 4 + r;
            float linv = 1.0f / L[z * NN + m];
#pragma unroll
            for (int j = 0; j < 8; ++j) {
                int n = n0 + wc * 128 + j * 16 + fc;
                Ob[(size_t)z * bnc + (size_t)m * NC + n] = f2bf(acc[i][j][r] * linv);
            }
        }
    }
}

// ---------------------------------------------------------------------------
extern "C" void kernel_launch(void* const* d_in, const int* in_sizes, int n_in,
                              void* d_out, int out_size, void* d_ws, size_t ws_size,
                              hipStream_t stream)
{
    const float* x     = (const float*)d_in[0];
    const float* gn_w  = (const float*)d_in[1];
    const float* gn_b  = (const float*)d_in[2];
    const float* qkv_w = (const float*)d_in[3];
    const float* qkv_b = (const float*)d_in[4];
    const float* out_w = (const float*)d_in[5];
    const float* out_b = (const float*)d_in[6];
    float* out = (float*)d_out;

    const size_t bnc = (size_t)NN * NC;          // 2,097,152 per batch
    char* w = (char*)d_ws;
    float* ss   = (float*)w;                 w += 16384;
    float* part = (float*)w;                 w += 8192;
    float* Lsum = (float*)w;                 w += (size_t)NB * NN * 4;  // row sums
    unsigned short* wq = (unsigned short*)w; w += (size_t)1536 * 512 * 2;
    unsigned short* wo = (unsigned short*)w; w += (size_t)512 * 512 * 2;
    unsigned short* qt = (unsigned short*)w; w += NB * bnc * 2;   // (b,n,c) pre-scaled
    unsigned short* kt = (unsigned short*)w; w += NB * bnc * 2;   // (b,n,c)
    unsigned short* vt = (unsigned short*)w; w += NB * bnc * 2;   // (b,c,n)
    unsigned short* SP = (unsigned short*)w; w += (size_t)NB * NN * NN * 2; // 128 MB
    // Aliases (lifetime-disjoint):
    unsigned short* ht = SP;   // ht (b,n,c) dead before MODE 2 writes SP
    unsigned short* Ob = qt;   // Ob (b,n,c) written after qt last read (MODE 2)

    hipMemsetAsync(Lsum, 0, (size_t)NB * NN * sizeof(float), stream);

    gn_partial_kernel<<<1024, 256, 0, stream>>>(x, part);
    gn_final_kernel<<<1, 128, 0, stream>>>(part, gn_w, gn_b, ss);
    wconv_kernel<<<(1536 * 512 + 512 * 512) / 256, 256, 0, stream>>>(qkv_w, out_w, wq, wo);
    htnorm_kernel<<<dim3(NN / 32, NC / 32, NB), 256, 0, stream>>>(x, ss, ht);

    // q/k: C[p,o] = ht · wqk^T   (q pre-scaled by ATTN_SCALE)
    mfma_gemm<0, 128, 128><<<dim3(1024 / 128, NN / 128, NB), 256, 0, stream>>>(
        ht, wq, qkv_b, nullptr, nullptr, qt, kt);
    // v: C[c,p] = wv · ht^T
    mfma_gemm<1, 128, 128><<<dim3(NN / 128, 512 / 128, NB), 256, 0, stream>>>(
        wq + (size_t)1024 * 512, ht, qkv_b, nullptr, nullptr, vt, nullptr);

    // QK^T + exp + row-sum accumulation, all batches, one dispatch
    mfma_gemm<2, 128, 128><<<dim3(NN / 128, NN / 128, NB), 256, 0, stream>>>(
        qt, kt, nullptr, nullptr, Lsum, SP, nullptr);
    // PV + normalize, all batches
    pv_gemm<<<dim3(512 / 256, NN / 64, NB), 256, 0, stream>>>(SP, vt, Lsum, Ob);

    // out projection + bias + residual
    mfma_gemm<4, 128, 128><<<dim3(NN / 128, 512 / 128, NB), 256, 0, stream>>>(
        wo, Ob, out_b, x, out, nullptr, nullptr);
}